// Round 1
// baseline (346.041 us; speedup 1.0000x reference)
//
#include <hip/hip_runtime.h>
#include <math.h>

#define EPSILON 0.3f
#define ALPHA 0.7f
#define LN_EPS 1e-5f

// All-threads block reduction; every thread returns the full sum.
__device__ __forceinline__ float blk_reduce_sum(float v, float* red) {
#pragma unroll
  for (int off = 32; off > 0; off >>= 1) v += __shfl_xor(v, off, 64);
  int lane = threadIdx.x & 63, wid = threadIdx.x >> 6;
  __syncthreads();
  if (lane == 0) red[wid] = v;
  __syncthreads();
  float s = 0.f;
  int nw = (blockDim.x + 63) >> 6;
  for (int w = 0; w < nw; ++w) s += red[w];
  return s;
}

// Per row i: y = x[i]@proj_w + proj_b ; LN(L=16) ; ReLU -> xp[i], s[i]=||xp||^2,
// pi[i] = sigmoid(relu(xp@pi_w1+pi_b1)@pi_w2 + pi_b2)
__global__ __launch_bounds__(256) void k_proj(
    const float* __restrict__ x, const float* __restrict__ proj_w,
    const float* __restrict__ proj_b, const float* __restrict__ ln1_g,
    const float* __restrict__ ln1_b, const float* __restrict__ pi_w1,
    const float* __restrict__ pi_b1, const float* __restrict__ pi_w2,
    const float* __restrict__ pi_b2, float* __restrict__ xp,
    float* __restrict__ s, float* __restrict__ pi, int N, int D) {
  const int L = 16;
  __shared__ float xs[768];
  __shared__ float ys[16];
  __shared__ float xps[16];
  __shared__ float red[4];
  int i = blockIdx.x, tid = threadIdx.x;
  for (int k = tid; k < D; k += 256) xs[k] = x[(size_t)i * D + k];
  __syncthreads();
  // 16 groups of 16 threads; group l computes y[l]
  int l = tid >> 4, j = tid & 15;
  float acc = 0.f;
  for (int k = j; k < D; k += 16) acc += xs[k] * proj_w[k * L + l];
  acc += __shfl_xor(acc, 8, 64);
  acc += __shfl_xor(acc, 4, 64);
  acc += __shfl_xor(acc, 2, 64);
  acc += __shfl_xor(acc, 1, 64);
  if (j == 0) ys[l] = acc + proj_b[l];
  __syncthreads();
  // LayerNorm over L=16 (computed redundantly by all threads)
  float mu = 0.f;
#pragma unroll
  for (int t = 0; t < 16; ++t) mu += ys[t];
  mu *= (1.f / 16.f);
  float var = 0.f;
#pragma unroll
  for (int t = 0; t < 16; ++t) { float d2 = ys[t] - mu; var += d2 * d2; }
  var *= (1.f / 16.f);
  float rstd = rsqrtf(var + LN_EPS);
  if (tid < 16) {
    float v = (ys[tid] - mu) * rstd * ln1_g[tid] + ln1_b[tid];
    v = fmaxf(v, 0.f);
    xps[tid] = v;
    xp[(size_t)i * L + tid] = v;
  }
  __syncthreads();
  if (tid == 0) {
    float ss = 0.f;
#pragma unroll
    for (int t = 0; t < 16; ++t) ss += xps[t] * xps[t];
    s[i] = ss;
  }
  // pi head
  float pacc = 0.f;
  for (int d0 = tid; d0 < D; d0 += 256) {
    float h = pi_b1[d0];
#pragma unroll
    for (int t = 0; t < 16; ++t) h += xps[t] * pi_w1[t * D + d0];
    h = fmaxf(h, 0.f);
    pacc += h * pi_w2[d0];
  }
  float tot = blk_reduce_sum(pacc, red);
  if (tid == 0) {
    float z = tot + pi_b2[0];
    pi[i] = 1.f / (1.f + expf(-z));
  }
}

// Row i of K_eps: K[i][j] = exp(-c*(s_i+s_j-2*dot)), q[i] = row sum
__global__ __launch_bounds__(256) void k_keps(
    const float* __restrict__ xp, const float* __restrict__ s,
    float* __restrict__ Kmat, float* __restrict__ q, int N) {
  __shared__ float red[4];
  int i = blockIdx.x, tid = threadIdx.x;
  const float4* a4 = (const float4*)(xp + (size_t)i * 16);
  float4 a0 = a4[0], a1 = a4[1], a2 = a4[2], a3 = a4[3];
  float si = s[i];
  const float c = 1.f / (4.f * EPSILON);
  float qacc = 0.f;
  for (int jj = tid; jj < N; jj += 256) {
    const float4* b4 = (const float4*)(xp + (size_t)jj * 16);
    float4 b0 = b4[0], b1 = b4[1], b2 = b4[2], b3 = b4[3];
    float dot = a0.x * b0.x + a0.y * b0.y + a0.z * b0.z + a0.w * b0.w +
                a1.x * b1.x + a1.y * b1.y + a1.z * b1.z + a1.w * b1.w +
                a2.x * b2.x + a2.y * b2.y + a2.z * b2.z + a2.w * b2.w +
                a3.x * b3.x + a3.y * b3.y + a3.z * b3.z + a3.w * b3.w;
    float dist = si + s[jj] - 2.f * dot;
    float kv = expf(-c * dist);
    Kmat[(size_t)i * N + jj] = kv;
    qacc += kv;
  }
  float tot = blk_reduce_sum(qacc, red);
  if (tid == 0) q[i] = tot;
}

// In-place column scale K *= v[j] (v = pi/q), row sums -> dv[i] = sum + 1e-5
__global__ __launch_bounds__(256) void k_scale(
    float* __restrict__ Kmat, const float* __restrict__ pi,
    const float* __restrict__ q, float* __restrict__ dv, int N) {
  __shared__ float red[4];
  int i = blockIdx.x, tid = threadIdx.x;
  float acc = 0.f;
  for (int jj = tid; jj < N; jj += 256) {
    float w = Kmat[(size_t)i * N + jj] * (pi[jj] / q[jj]);
    Kmat[(size_t)i * N + jj] = w;
    acc += w;
  }
  float tot = blk_reduce_sum(acc, red);
  if (tid == 0) dv[i] = tot + 1e-5f;
}

// C[M,N] = A[M,K] @ B[K,N] + bias[N]; 64x64 tile, 4x4 per thread, BK=16
__global__ __launch_bounds__(256) void k_gemm_bias(
    const float* __restrict__ A, const float* __restrict__ B,
    const float* __restrict__ bias, float* __restrict__ C, int M, int N, int K) {
  __shared__ float As[16][65];
  __shared__ float Bs[16][64];
  int tid = threadIdx.x;
  int row0 = blockIdx.y * 64, col0 = blockIdx.x * 64;
  int tx = tid & 15, ty = tid >> 4;
  int arow = tid >> 2, acol = (tid & 3) * 4;
  int brow = tid >> 4, bcol = (tid & 15) * 4;
  float acc[4][4] = {};
  for (int k0 = 0; k0 < K; k0 += 16) {
    float4 av = *(const float4*)(A + (size_t)(row0 + arow) * K + k0 + acol);
    float4 bv = *(const float4*)(B + (size_t)(k0 + brow) * N + col0 + bcol);
    __syncthreads();
    As[acol + 0][arow] = av.x;
    As[acol + 1][arow] = av.y;
    As[acol + 2][arow] = av.z;
    As[acol + 3][arow] = av.w;
    *((float4*)&Bs[brow][bcol]) = bv;
    __syncthreads();
#pragma unroll
    for (int kk = 0; kk < 16; ++kk) {
      float a0 = As[kk][ty * 4 + 0], a1 = As[kk][ty * 4 + 1];
      float a2 = As[kk][ty * 4 + 2], a3 = As[kk][ty * 4 + 3];
      float b0 = Bs[kk][tx * 4 + 0], b1 = Bs[kk][tx * 4 + 1];
      float b2 = Bs[kk][tx * 4 + 2], b3 = Bs[kk][tx * 4 + 3];
      acc[0][0] += a0 * b0; acc[0][1] += a0 * b1; acc[0][2] += a0 * b2; acc[0][3] += a0 * b3;
      acc[1][0] += a1 * b0; acc[1][1] += a1 * b1; acc[1][2] += a1 * b2; acc[1][3] += a1 * b3;
      acc[2][0] += a2 * b0; acc[2][1] += a2 * b1; acc[2][2] += a2 * b2; acc[2][3] += a2 * b3;
      acc[3][0] += a3 * b0; acc[3][1] += a3 * b1; acc[3][2] += a3 * b2; acc[3][3] += a3 * b3;
    }
  }
#pragma unroll
  for (int r = 0; r < 4; ++r) {
    int row = row0 + ty * 4 + r;
#pragma unroll
    for (int cc = 0; cc < 4; ++cc) {
      int col = col0 + tx * 4 + cc;
      C[(size_t)row * N + col] = acc[r][cc] + bias[col];
    }
  }
}

// acc = W[M,K] @ T[K,N]; epilogue:
// out = ALPHA*x + (1-ALPHA)*(1-2dt)*T + ((1-ALPHA)*2dt/EPS)/dv[row] * acc
__global__ __launch_bounds__(256) void k_gemm_tt(
    const float* __restrict__ W, const float* __restrict__ T,
    const float* __restrict__ x, const float* __restrict__ dv,
    const float* __restrict__ dtp, float* __restrict__ out, int M, int N, int K) {
  __shared__ float As[16][65];
  __shared__ float Bs[16][64];
  int tid = threadIdx.x;
  int row0 = blockIdx.y * 64, col0 = blockIdx.x * 64;
  int tx = tid & 15, ty = tid >> 4;
  int arow = tid >> 2, acol = (tid & 3) * 4;
  int brow = tid >> 4, bcol = (tid & 15) * 4;
  float acc[4][4] = {};
  for (int k0 = 0; k0 < K; k0 += 16) {
    float4 av = *(const float4*)(W + (size_t)(row0 + arow) * K + k0 + acol);
    float4 bv = *(const float4*)(T + (size_t)(k0 + brow) * N + col0 + bcol);
    __syncthreads();
    As[acol + 0][arow] = av.x;
    As[acol + 1][arow] = av.y;
    As[acol + 2][arow] = av.z;
    As[acol + 3][arow] = av.w;
    *((float4*)&Bs[brow][bcol]) = bv;
    __syncthreads();
#pragma unroll
    for (int kk = 0; kk < 16; ++kk) {
      float a0 = As[kk][ty * 4 + 0], a1 = As[kk][ty * 4 + 1];
      float a2 = As[kk][ty * 4 + 2], a3 = As[kk][ty * 4 + 3];
      float b0 = Bs[kk][tx * 4 + 0], b1 = Bs[kk][tx * 4 + 1];
      float b2 = Bs[kk][tx * 4 + 2], b3 = Bs[kk][tx * 4 + 3];
      acc[0][0] += a0 * b0; acc[0][1] += a0 * b1; acc[0][2] += a0 * b2; acc[0][3] += a0 * b3;
      acc[1][0] += a1 * b0; acc[1][1] += a1 * b1; acc[1][2] += a1 * b2; acc[1][3] += a1 * b3;
      acc[2][0] += a2 * b0; acc[2][1] += a2 * b1; acc[2][2] += a2 * b2; acc[2][3] += a2 * b3;
      acc[3][0] += a3 * b0; acc[3][1] += a3 * b1; acc[3][2] += a3 * b2; acc[3][3] += a3 * b3;
    }
  }
  float dtv = dtp[0];
  float c2 = (1.f - ALPHA) * (1.f - 2.f * dtv);
  float c3b = (1.f - ALPHA) * 2.f * dtv / EPSILON;
#pragma unroll
  for (int r = 0; r < 4; ++r) {
    int row = row0 + ty * 4 + r;
    float c3 = c3b / dv[row];
#pragma unroll
    for (int cc = 0; cc < 4; ++cc) {
      int col = col0 + tx * 4 + cc;
      size_t idx = (size_t)row * N + col;
      out[idx] = ALPHA * x[idx] + c2 * T[idx] + c3 * acc[r][cc];
    }
  }
}

// In-place LayerNorm over rows of out (D elements, D/256 <= 4)
__global__ __launch_bounds__(256) void k_ln_rows(
    float* __restrict__ out, const float* __restrict__ g,
    const float* __restrict__ b, int D) {
  __shared__ float red[4];
  int i = blockIdx.x, tid = threadIdx.x;
  float v[4];
  int nt = D / 256;
  float sum = 0.f;
  for (int t = 0; t < nt; ++t) {
    v[t] = out[(size_t)i * D + tid + t * 256];
    sum += v[t];
  }
  float mu = blk_reduce_sum(sum, red) / (float)D;
  float sq = 0.f;
  for (int t = 0; t < nt; ++t) { float d2 = v[t] - mu; sq += d2 * d2; }
  float var = blk_reduce_sum(sq, red) / (float)D;
  float rs = rsqrtf(var + LN_EPS);
  for (int t = 0; t < nt; ++t) {
    int d0 = tid + t * 256;
    out[(size_t)i * D + d0] = (v[t] - mu) * rs * g[d0] + b[d0];
  }
}

extern "C" void kernel_launch(void* const* d_in, const int* in_sizes, int n_in,
                              void* d_out, int out_size, void* d_ws, size_t ws_size,
                              hipStream_t stream) {
  const float* x = (const float*)d_in[0];
  const float* proj_w = (const float*)d_in[1];
  const float* proj_b = (const float*)d_in[2];
  const float* ln1_g = (const float*)d_in[3];
  const float* ln1_b = (const float*)d_in[4];
  const float* pi_w1 = (const float*)d_in[5];
  const float* pi_b1 = (const float*)d_in[6];
  const float* pi_w2 = (const float*)d_in[7];
  const float* pi_b2 = (const float*)d_in[8];
  const float* dt = (const float*)d_in[9];
  const float* f_w = (const float*)d_in[10];
  const float* f_b = (const float*)d_in[11];
  const float* ln2_g = (const float*)d_in[12];
  const float* ln2_b = (const float*)d_in[13];
  float* out = (float*)d_out;

  const int L = 16;
  int D = in_sizes[11];      // 768
  int N = in_sizes[0] / D;   // 2048

  float* ws = (float*)d_ws;
  float* Kmat = ws;                          // N*N
  float* T = Kmat + (size_t)N * N;           // N*D
  float* xp = T + (size_t)N * D;             // N*L
  float* s = xp + (size_t)N * L;             // N
  float* pi = s + N;                         // N
  float* q = pi + N;                         // N
  float* dv = q + N;                         // N

  k_proj<<<N, 256, 0, stream>>>(x, proj_w, proj_b, ln1_g, ln1_b, pi_w1, pi_b1,
                                pi_w2, pi_b2, xp, s, pi, N, D);
  k_keps<<<N, 256, 0, stream>>>(xp, s, Kmat, q, N);
  k_scale<<<N, 256, 0, stream>>>(Kmat, pi, q, dv, N);
  k_gemm_bias<<<dim3(D / 64, N / 64), 256, 0, stream>>>(x, f_w, f_b, T, N, D, D);
  k_gemm_tt<<<dim3(D / 64, N / 64), 256, 0, stream>>>(Kmat, T, x, dv, dt, out, N, D, N);
  k_ln_rows<<<N, 256, 0, stream>>>(out, ln2_g, ln2_b, D);
}

// Round 2
// 214.958 us; speedup vs baseline: 1.6098x; 1.6098x over previous
//
#include <hip/hip_runtime.h>
#include <math.h>

#define EPSILON 0.3f
#define ALPHA 0.7f
#define LN_EPS 1e-5f

typedef __bf16 bf16x8 __attribute__((ext_vector_type(8)));
typedef float f32x4 __attribute__((ext_vector_type(4)));

__device__ __forceinline__ unsigned short f2bf(float f) {
  unsigned int u = __float_as_uint(f);
  return (unsigned short)((u + 0x7fffu + ((u >> 16) & 1u)) >> 16);
}
__device__ __forceinline__ float bf2f(unsigned short h) {
  return __uint_as_float(((unsigned int)h) << 16);
}
__device__ __forceinline__ unsigned int pack2(float lo, float hi) {
  return (unsigned int)f2bf(lo) | ((unsigned int)f2bf(hi) << 16);
}

// All-threads block reduction; every thread returns the full sum.
__device__ __forceinline__ float blk_reduce_sum(float v, float* red) {
#pragma unroll
  for (int off = 32; off > 0; off >>= 1) v += __shfl_xor(v, off, 64);
  int lane = threadIdx.x & 63, wid = threadIdx.x >> 6;
  __syncthreads();
  if (lane == 0) red[wid] = v;
  __syncthreads();
  float s = 0.f;
  int nw = (blockDim.x + 63) >> 6;
  for (int w = 0; w < nw; ++w) s += red[w];
  return s;
}

// Per row i: y = x[i]@proj_w + proj_b ; LN(L=16) ; ReLU -> xp[i], s[i]=||xp||^2,
// pi[i] = sigmoid(relu(xp@pi_w1+pi_b1)@pi_w2 + pi_b2)
__global__ __launch_bounds__(256) void k_proj(
    const float* __restrict__ x, const float* __restrict__ proj_w,
    const float* __restrict__ proj_b, const float* __restrict__ ln1_g,
    const float* __restrict__ ln1_b, const float* __restrict__ pi_w1,
    const float* __restrict__ pi_b1, const float* __restrict__ pi_w2,
    const float* __restrict__ pi_b2, float* __restrict__ xp,
    float* __restrict__ s, float* __restrict__ pi, int N, int D) {
  const int L = 16;
  __shared__ float xs[768];
  __shared__ float ys[16];
  __shared__ float xps[16];
  __shared__ float red[4];
  int i = blockIdx.x, tid = threadIdx.x;
  for (int k = tid; k < D; k += 256) xs[k] = x[(size_t)i * D + k];
  __syncthreads();
  int l = tid >> 4, j = tid & 15;
  float acc = 0.f;
  for (int k = j; k < D; k += 16) acc += xs[k] * proj_w[k * L + l];
  acc += __shfl_xor(acc, 8, 64);
  acc += __shfl_xor(acc, 4, 64);
  acc += __shfl_xor(acc, 2, 64);
  acc += __shfl_xor(acc, 1, 64);
  if (j == 0) ys[l] = acc + proj_b[l];
  __syncthreads();
  float mu = 0.f;
#pragma unroll
  for (int t = 0; t < 16; ++t) mu += ys[t];
  mu *= (1.f / 16.f);
  float var = 0.f;
#pragma unroll
  for (int t = 0; t < 16; ++t) { float d2 = ys[t] - mu; var += d2 * d2; }
  var *= (1.f / 16.f);
  float rstd = rsqrtf(var + LN_EPS);
  if (tid < 16) {
    float v = (ys[tid] - mu) * rstd * ln1_g[tid] + ln1_b[tid];
    v = fmaxf(v, 0.f);
    xps[tid] = v;
    xp[(size_t)i * L + tid] = v;
  }
  __syncthreads();
  if (tid == 0) {
    float ss = 0.f;
#pragma unroll
    for (int t = 0; t < 16; ++t) ss += xps[t] * xps[t];
    s[i] = ss;
  }
  float pacc = 0.f;
  for (int d0 = tid; d0 < D; d0 += 256) {
    float h = pi_b1[d0];
#pragma unroll
    for (int t = 0; t < 16; ++t) h += xps[t] * pi_w1[t * D + d0];
    h = fmaxf(h, 0.f);
    pacc += h * pi_w2[d0];
  }
  float tot = blk_reduce_sum(pacc, red);
  if (tid == 0) {
    float z = tot + pi_b2[0];
    pi[i] = 1.f / (1.f + expf(-z));
  }
}

// Row i of K_eps: Kb[i][j] = bf16(exp(-c*(s_i+s_j-2*dot))), q[i] = fp32 row sum
__global__ __launch_bounds__(256) void k_keps(
    const float* __restrict__ xp, const float* __restrict__ s,
    unsigned short* __restrict__ Kb, float* __restrict__ q, int N) {
  __shared__ float red[4];
  int i = blockIdx.x, tid = threadIdx.x;
  const float4* a4 = (const float4*)(xp + (size_t)i * 16);
  float4 a0 = a4[0], a1 = a4[1], a2 = a4[2], a3 = a4[3];
  float si = s[i];
  const float c = 1.f / (4.f * EPSILON);
  float qacc = 0.f;
  for (int jj = tid; jj < N; jj += 256) {
    const float4* b4 = (const float4*)(xp + (size_t)jj * 16);
    float4 b0 = b4[0], b1 = b4[1], b2 = b4[2], b3 = b4[3];
    float dot = a0.x * b0.x + a0.y * b0.y + a0.z * b0.z + a0.w * b0.w +
                a1.x * b1.x + a1.y * b1.y + a1.z * b1.z + a1.w * b1.w +
                a2.x * b2.x + a2.y * b2.y + a2.z * b2.z + a2.w * b2.w +
                a3.x * b3.x + a3.y * b3.y + a3.z * b3.z + a3.w * b3.w;
    float dist = si + s[jj] - 2.f * dot;
    float kv = expf(-c * dist);
    Kb[(size_t)i * N + jj] = f2bf(kv);
    qacc += kv;
  }
  float tot = blk_reduce_sum(qacc, red);
  if (tid == 0) q[i] = tot;
}

// v[j] = pi[j]/q[j]
__global__ __launch_bounds__(256) void k_v(const float* __restrict__ pi,
                                           const float* __restrict__ q,
                                           float* __restrict__ v, int N) {
  int j = blockIdx.x * 256 + threadIdx.x;
  if (j < N) v[j] = pi[j] / q[j];
}

// dv[i] = sum_j bf16K[i][j]*v[j] + 1e-5 (matches exactly what the GEMM consumes)
__global__ __launch_bounds__(256) void k_scale_bf(
    const unsigned short* __restrict__ Kb, const float* __restrict__ v,
    float* __restrict__ dv, int N) {
  __shared__ float red[4];
  int i = blockIdx.x, tid = threadIdx.x;
  float acc = 0.f;
  for (int jj = tid; jj < N; jj += 256)
    acc += bf2f(Kb[(size_t)i * N + jj]) * v[jj];
  float tot = blk_reduce_sum(acc, red);
  if (tid == 0) dv[i] = tot + 1e-5f;
}

// dst[c][r] = bf16( (vscale ? vscale[r] : 1) * src[r][c] ); src [R][C] f32, dst [C][R] bf16
__global__ __launch_bounds__(256) void k_tcvt(
    const float* __restrict__ src, unsigned short* __restrict__ dst,
    int R, int C, const float* __restrict__ vscale) {
  __shared__ unsigned short tile[32][33];
  int tx = threadIdx.x & 31, ty = threadIdx.x >> 5;  // ty 0..7
  int r0 = blockIdx.y * 32, c0 = blockIdx.x * 32;
#pragma unroll
  for (int i = 0; i < 4; ++i) {
    int r = r0 + ty + i * 8;
    float f = src[(size_t)r * C + c0 + tx];
    if (vscale) f *= vscale[r];
    tile[ty + i * 8][tx] = f2bf(f);
  }
  __syncthreads();
#pragma unroll
  for (int i = 0; i < 4; ++i) {
    int cc = c0 + ty + i * 8;
    dst[(size_t)cc * R + r0 + tx] = tile[tx][ty + i * 8];
  }
}

// T[M][N] = x[M][K](f32, cvt on the fly) @ Bt[N][K]^T (bf16) + bias[N]
// 64x64 tile, 4 waves in 2x2, mfma 16x16x32 bf16, BK=64
__global__ __launch_bounds__(256) void k_gemm1(
    const float* __restrict__ x, const unsigned short* __restrict__ Bt,
    const float* __restrict__ bias, float* __restrict__ T,
    int M, int N, int K) {
  __shared__ unsigned short As[64][72];
  __shared__ unsigned short Bs[64][72];
  int tid = threadIdx.x;
  int w = tid >> 6, l = tid & 63;
  int ln = l & 15, quad = l >> 4;
  int mh = (w & 1) * 32, nh = (w >> 1) * 32;
  int row0 = blockIdx.y * 64, col0 = blockIdx.x * 64;
  int lr = tid >> 3, lc = (tid & 7) * 8;
  f32x4 acc[2][2] = {};
  for (int k0 = 0; k0 < K; k0 += 64) {
    float4 a00 = *(const float4*)(x + (size_t)(row0 + lr) * K + k0 + lc);
    float4 a01 = *(const float4*)(x + (size_t)(row0 + lr) * K + k0 + lc + 4);
    float4 a10 = *(const float4*)(x + (size_t)(row0 + lr + 32) * K + k0 + lc);
    float4 a11 = *(const float4*)(x + (size_t)(row0 + lr + 32) * K + k0 + lc + 4);
    uint4 b0 = *(const uint4*)(Bt + (size_t)(col0 + lr) * K + k0 + lc);
    uint4 b1 = *(const uint4*)(Bt + (size_t)(col0 + lr + 32) * K + k0 + lc);
    __syncthreads();
    *(uint4*)&As[lr][lc] =
        make_uint4(pack2(a00.x, a00.y), pack2(a00.z, a00.w),
                   pack2(a01.x, a01.y), pack2(a01.z, a01.w));
    *(uint4*)&As[lr + 32][lc] =
        make_uint4(pack2(a10.x, a10.y), pack2(a10.z, a10.w),
                   pack2(a11.x, a11.y), pack2(a11.z, a11.w));
    *(uint4*)&Bs[lr][lc] = b0;
    *(uint4*)&Bs[lr + 32][lc] = b1;
    __syncthreads();
#pragma unroll
    for (int ks = 0; ks < 2; ++ks) {
      bf16x8 bfr[2], afr[2];
#pragma unroll
      for (int nt = 0; nt < 2; ++nt)
        bfr[nt] = *(const bf16x8*)&Bs[nh + nt * 16 + ln][ks * 32 + quad * 8];
#pragma unroll
      for (int mt = 0; mt < 2; ++mt)
        afr[mt] = *(const bf16x8*)&As[mh + mt * 16 + ln][ks * 32 + quad * 8];
#pragma unroll
      for (int mt = 0; mt < 2; ++mt)
#pragma unroll
        for (int nt = 0; nt < 2; ++nt)
          acc[mt][nt] = __builtin_amdgcn_mfma_f32_16x16x32_bf16(
              afr[mt], bfr[nt], acc[mt][nt], 0, 0, 0);
    }
  }
#pragma unroll
  for (int mt = 0; mt < 2; ++mt)
#pragma unroll
    for (int nt = 0; nt < 2; ++nt) {
      int col = col0 + nh + nt * 16 + ln;
      float bv = bias[col];
#pragma unroll
      for (int r = 0; r < 4; ++r) {
        int row = row0 + mh + mt * 16 + quad * 4 + r;
        T[(size_t)row * N + col] = acc[mt][nt][r] + bv;
      }
    }
}

// acc = Kb[M][K] @ Ttb[N][K]^T (both bf16); epilogue:
// out = ALPHA*x + (1-ALPHA)*(1-2dt)*T + ((1-ALPHA)*2dt/EPS)/dv[row] * acc
__global__ __launch_bounds__(256) void k_gemm2(
    const unsigned short* __restrict__ A, const unsigned short* __restrict__ Bt,
    const float* __restrict__ x, const float* __restrict__ T,
    const float* __restrict__ dv, const float* __restrict__ dtp,
    float* __restrict__ out, int M, int N, int K) {
  __shared__ unsigned short As[64][72];
  __shared__ unsigned short Bs[64][72];
  int tid = threadIdx.x;
  int w = tid >> 6, l = tid & 63;
  int ln = l & 15, quad = l >> 4;
  int mh = (w & 1) * 32, nh = (w >> 1) * 32;
  int row0 = blockIdx.y * 64, col0 = blockIdx.x * 64;
  int lr = tid >> 3, lc = (tid & 7) * 8;
  f32x4 acc[2][2] = {};
  for (int k0 = 0; k0 < K; k0 += 64) {
    uint4 a0 = *(const uint4*)(A + (size_t)(row0 + lr) * K + k0 + lc);
    uint4 a1 = *(const uint4*)(A + (size_t)(row0 + lr + 32) * K + k0 + lc);
    uint4 b0 = *(const uint4*)(Bt + (size_t)(col0 + lr) * K + k0 + lc);
    uint4 b1 = *(const uint4*)(Bt + (size_t)(col0 + lr + 32) * K + k0 + lc);
    __syncthreads();
    *(uint4*)&As[lr][lc] = a0;
    *(uint4*)&As[lr + 32][lc] = a1;
    *(uint4*)&Bs[lr][lc] = b0;
    *(uint4*)&Bs[lr + 32][lc] = b1;
    __syncthreads();
#pragma unroll
    for (int ks = 0; ks < 2; ++ks) {
      bf16x8 bfr[2], afr[2];
#pragma unroll
      for (int nt = 0; nt < 2; ++nt)
        bfr[nt] = *(const bf16x8*)&Bs[nh + nt * 16 + ln][ks * 32 + quad * 8];
#pragma unroll
      for (int mt = 0; mt < 2; ++mt)
        afr[mt] = *(const bf16x8*)&As[mh + mt * 16 + ln][ks * 32 + quad * 8];
#pragma unroll
      for (int mt = 0; mt < 2; ++mt)
#pragma unroll
        for (int nt = 0; nt < 2; ++nt)
          acc[mt][nt] = __builtin_amdgcn_mfma_f32_16x16x32_bf16(
              afr[mt], bfr[nt], acc[mt][nt], 0, 0, 0);
    }
  }
  float dtv = dtp[0];
  float c2 = (1.f - ALPHA) * (1.f - 2.f * dtv);
  float c3b = (1.f - ALPHA) * 2.f * dtv / EPSILON;
#pragma unroll
  for (int mt = 0; mt < 2; ++mt)
#pragma unroll
    for (int nt = 0; nt < 2; ++nt) {
      int col = col0 + nh + nt * 16 + ln;
#pragma unroll
      for (int r = 0; r < 4; ++r) {
        int row = row0 + mh + mt * 16 + quad * 4 + r;
        size_t idx = (size_t)row * N + col;
        float c3 = c3b / dv[row];
        out[idx] = ALPHA * x[idx] + c2 * T[idx] + c3 * acc[mt][nt][r];
      }
    }
}

// In-place LayerNorm over rows of out (D elements, D/256 <= 4)
__global__ __launch_bounds__(256) void k_ln_rows(
    float* __restrict__ out, const float* __restrict__ g,
    const float* __restrict__ b, int D) {
  __shared__ float red[4];
  int i = blockIdx.x, tid = threadIdx.x;
  float v[4];
  int nt = D / 256;
  float sum = 0.f;
  for (int t = 0; t < nt; ++t) {
    v[t] = out[(size_t)i * D + tid + t * 256];
    sum += v[t];
  }
  float mu = blk_reduce_sum(sum, red) / (float)D;
  float sq = 0.f;
  for (int t = 0; t < nt; ++t) { float d2 = v[t] - mu; sq += d2 * d2; }
  float var = blk_reduce_sum(sq, red) / (float)D;
  float rs = rsqrtf(var + LN_EPS);
  for (int t = 0; t < nt; ++t) {
    int d0 = tid + t * 256;
    out[(size_t)i * D + d0] = (v[t] - mu) * rs * g[d0] + b[d0];
  }
}

extern "C" void kernel_launch(void* const* d_in, const int* in_sizes, int n_in,
                              void* d_out, int out_size, void* d_ws, size_t ws_size,
                              hipStream_t stream) {
  const float* x = (const float*)d_in[0];
  const float* proj_w = (const float*)d_in[1];
  const float* proj_b = (const float*)d_in[2];
  const float* ln1_g = (const float*)d_in[3];
  const float* ln1_b = (const float*)d_in[4];
  const float* pi_w1 = (const float*)d_in[5];
  const float* pi_b1 = (const float*)d_in[6];
  const float* pi_w2 = (const float*)d_in[7];
  const float* pi_b2 = (const float*)d_in[8];
  const float* dt = (const float*)d_in[9];
  const float* f_w = (const float*)d_in[10];
  const float* f_b = (const float*)d_in[11];
  const float* ln2_g = (const float*)d_in[12];
  const float* ln2_b = (const float*)d_in[13];
  float* out = (float*)d_out;

  int D = in_sizes[11];      // 768
  int N = in_sizes[0] / D;   // 2048

  // Workspace layout (~19.2 MB, all segments 16B-aligned)
  unsigned short* Kb = (unsigned short*)d_ws;            // N*N bf16
  float* T = (float*)(Kb + (size_t)N * N);               // N*D f32
  unsigned short* Ttb = (unsigned short*)(T + (size_t)N * D);  // D*N bf16 ((v*T)^T)
  unsigned short* fwTb = Ttb + (size_t)D * N;            // D*D bf16 (f_w^T)
  float* xp = (float*)(fwTb + (size_t)D * D);            // N*16
  float* s = xp + (size_t)N * 16;                        // N
  float* pi = s + N;                                     // N
  float* q = pi + N;                                     // N
  float* v = q + N;                                      // N
  float* dv = v + N;                                     // N

  k_proj<<<N, 256, 0, stream>>>(x, proj_w, proj_b, ln1_g, ln1_b, pi_w1, pi_b1,
                                pi_w2, pi_b2, xp, s, pi, N, D);
  k_keps<<<N, 256, 0, stream>>>(xp, s, Kb, q, N);
  k_v<<<(N + 255) / 256, 256, 0, stream>>>(pi, q, v, N);
  k_scale_bf<<<N, 256, 0, stream>>>(Kb, v, dv, N);
  k_tcvt<<<dim3(D / 32, D / 32), 256, 0, stream>>>(f_w, fwTb, D, D, nullptr);
  k_gemm1<<<dim3(D / 64, N / 64), 256, 0, stream>>>(x, fwTb, f_b, T, N, D, D);
  k_tcvt<<<dim3(D / 32, N / 32), 256, 0, stream>>>(T, Ttb, N, D, v);
  k_gemm2<<<dim3(D / 64, N / 64), 256, 0, stream>>>(Kb, Ttb, x, T, dv, dt, out,
                                                    N, D, N);
  k_ln_rows<<<N, 256, 0, stream>>>(out, ln2_g, ln2_b, D);
}

// Round 3
// 167.650 us; speedup vs baseline: 2.0641x; 1.2822x over previous
//
#include <hip/hip_runtime.h>
#include <math.h>

#define EPSILON 0.3f
#define ALPHA 0.7f
#define LN_EPS 1e-5f

typedef __bf16 bf16x8 __attribute__((ext_vector_type(8)));
typedef float f32x4 __attribute__((ext_vector_type(4)));

__device__ __forceinline__ unsigned short f2bf(float f) {
  unsigned int u = __float_as_uint(f);
  return (unsigned short)((u + 0x7fffu + ((u >> 16) & 1u)) >> 16);
}
__device__ __forceinline__ float bf2f(unsigned short h) {
  return __uint_as_float(((unsigned int)h) << 16);
}
__device__ __forceinline__ unsigned int pack2(float lo, float hi) {
  return (unsigned int)f2bf(lo) | ((unsigned int)f2bf(hi) << 16);
}

__device__ __forceinline__ float wave_reduce(float v) {
#pragma unroll
  for (int off = 32; off > 0; off >>= 1) v += __shfl_xor(v, off, 64);
  return v;
}

// All-threads block reduction; every thread returns the full sum.
__device__ __forceinline__ float blk_reduce_sum(float v, float* red) {
  v = wave_reduce(v);
  int lane = threadIdx.x & 63, wid = threadIdx.x >> 6;
  __syncthreads();
  if (lane == 0) red[wid] = v;
  __syncthreads();
  float s = 0.f;
  int nw = (blockDim.x + 63) >> 6;
  for (int w = 0; w < nw; ++w) s += red[w];
  return s;
}

// 16 rows per block. proj -> LN -> ReLU -> xp, s ; pi head with register weights.
// Assumes D == 768 (3 chunks of 256), L == 16.
__global__ __launch_bounds__(256) void k_proj(
    const float* __restrict__ x, const float* __restrict__ proj_w,
    const float* __restrict__ proj_b, const float* __restrict__ ln1_g,
    const float* __restrict__ ln1_b, const float* __restrict__ pi_w1,
    const float* __restrict__ pi_b1, const float* __restrict__ pi_w2,
    const float* __restrict__ pi_b2, float* __restrict__ xp,
    float* __restrict__ s, float* __restrict__ pi, int N, int D) {
  __shared__ float xs[16][68];
  __shared__ float ws[64][20];
  __shared__ float ysh[16][17];
  __shared__ float xps[16][16];
  __shared__ float pr[16][4];
  int tid = threadIdx.x;
  int row0 = blockIdx.x * 16;
  int row = tid >> 4, l = tid & 15;
  int lane = tid & 63, w = tid >> 6;
  int skc = (tid & 15) * 4;           // xs stage: row=tid>>4, 4 cols
  int wk = tid >> 2, wl = (tid & 3) * 4;  // ws stage
  float acc = 0.f;
  for (int k0 = 0; k0 < D; k0 += 64) {
    float4 xv = *(const float4*)(x + (size_t)(row0 + row) * D + k0 + skc);
    float4 wv = *(const float4*)(proj_w + (size_t)(k0 + wk) * 16 + wl);
    __syncthreads();
    *(float4*)&xs[row][skc] = xv;
    *(float4*)&ws[wk][wl] = wv;
    __syncthreads();
#pragma unroll
    for (int kk = 0; kk < 64; kk += 4) {
      float4 a4 = *(const float4*)&xs[row][kk];
      acc += a4.x * ws[kk + 0][l];
      acc += a4.y * ws[kk + 1][l];
      acc += a4.z * ws[kk + 2][l];
      acc += a4.w * ws[kk + 3][l];
    }
  }
  float y = acc + proj_b[l];
  ysh[row][l] = y;
  __syncthreads();
  float mu = 0.f;
#pragma unroll
  for (int t = 0; t < 16; ++t) mu += ysh[row][t];
  mu *= (1.f / 16.f);
  float var = 0.f;
#pragma unroll
  for (int t = 0; t < 16; ++t) { float d2 = ysh[row][t] - mu; var += d2 * d2; }
  var *= (1.f / 16.f);
  float rstd = rsqrtf(var + LN_EPS);
  float xpv = fmaxf((y - mu) * rstd * ln1_g[l] + ln1_b[l], 0.f);
  xps[row][l] = xpv;
  xp[(size_t)(row0 + row) * 16 + l] = xpv;
  float sq = xpv * xpv;
  sq += __shfl_xor(sq, 8, 64);
  sq += __shfl_xor(sq, 4, 64);
  sq += __shfl_xor(sq, 2, 64);
  sq += __shfl_xor(sq, 1, 64);
  if ((lane & 15) == 0) s[row0 + row] = sq;
  __syncthreads();
  // pi head: thread owns d = tid + c*256, c<3; weights in registers
  float w1r[3][16], b1r[3], w2r[3];
#pragma unroll
  for (int c = 0; c < 3; ++c) {
    int d0 = tid + c * 256;
    b1r[c] = pi_b1[d0];
    w2r[c] = pi_w2[d0];
#pragma unroll
    for (int t = 0; t < 16; ++t) w1r[c][t] = pi_w1[(size_t)t * D + d0];
  }
  float pacc[16];
#pragma unroll
  for (int r = 0; r < 16; ++r) pacc[r] = 0.f;
#pragma unroll
  for (int r = 0; r < 16; ++r) {
    float xv[16];
#pragma unroll
    for (int t4 = 0; t4 < 4; ++t4) {
      float4 xq = *(const float4*)&xps[r][t4 * 4];
      xv[t4 * 4 + 0] = xq.x; xv[t4 * 4 + 1] = xq.y;
      xv[t4 * 4 + 2] = xq.z; xv[t4 * 4 + 3] = xq.w;
    }
    float pa = 0.f;
#pragma unroll
    for (int c = 0; c < 3; ++c) {
      float h = b1r[c];
#pragma unroll
      for (int t = 0; t < 16; ++t) h += xv[t] * w1r[c][t];
      h = fmaxf(h, 0.f);
      pa += h * w2r[c];
    }
    pacc[r] = pa;
  }
#pragma unroll
  for (int r = 0; r < 16; ++r) {
    float pv = wave_reduce(pacc[r]);
    if (lane == 0) pr[r][w] = pv;
  }
  __syncthreads();
  if (tid < 16) {
    float tot = pr[tid][0] + pr[tid][1] + pr[tid][2] + pr[tid][3] + pi_b2[0];
    pi[row0 + tid] = 1.f / (1.f + expf(-tot));
  }
}

// 4 rows per block; row fragments in (uniform) registers; writes Kb bf16,
// q[i] = fp32 row sum, v[i] = pi[i]/q[i].
__global__ __launch_bounds__(256) void k_keps(
    const float* __restrict__ xp, const float* __restrict__ s,
    const float* __restrict__ pi, unsigned short* __restrict__ Kb,
    float* __restrict__ q, float* __restrict__ v, int N) {
  __shared__ float qs[4][4];
  int i0 = blockIdx.x * 4;
  int tid = threadIdx.x, lane = tid & 63, w = tid >> 6;
  float a[4][16], si[4];
#pragma unroll
  for (int r = 0; r < 4; ++r) {
    const float* ap = xp + (size_t)(i0 + r) * 16;
#pragma unroll
    for (int t = 0; t < 16; ++t) a[r][t] = ap[t];
    si[r] = s[i0 + r];
  }
  const float c = 1.f / (4.f * EPSILON);
  float qa[4] = {0.f, 0.f, 0.f, 0.f};
  for (int it = 0; it < N / 256; ++it) {
    int j = it * 256 + tid;
    const float4* bp = (const float4*)(xp + (size_t)j * 16);
    float4 b0 = bp[0], b1 = bp[1], b2 = bp[2], b3 = bp[3];
    float bv[16] = {b0.x, b0.y, b0.z, b0.w, b1.x, b1.y, b1.z, b1.w,
                    b2.x, b2.y, b2.z, b2.w, b3.x, b3.y, b3.z, b3.w};
    float sj = s[j];
#pragma unroll
    for (int r = 0; r < 4; ++r) {
      float dot = 0.f;
#pragma unroll
      for (int t = 0; t < 16; ++t) dot += a[r][t] * bv[t];
      float kv = expf(-c * (si[r] + sj - 2.f * dot));
      Kb[(size_t)(i0 + r) * N + j] = f2bf(kv);
      qa[r] += kv;
    }
  }
#pragma unroll
  for (int r = 0; r < 4; ++r) {
    float t = wave_reduce(qa[r]);
    if (lane == 0) qs[r][w] = t;
  }
  __syncthreads();
  if (tid < 4) {
    float tot = qs[tid][0] + qs[tid][1] + qs[tid][2] + qs[tid][3];
    q[i0 + tid] = tot;
    v[i0 + tid] = pi[i0 + tid] / tot;
  }
}

// dv[i] = sum_j bf16K[i][j]*v[j] + 1e-5, vectorized uint4 (8 bf16) loads
__global__ __launch_bounds__(256) void k_scale_bf(
    const unsigned short* __restrict__ Kb, const float* __restrict__ v,
    float* __restrict__ dv, int N) {
  __shared__ float red[4];
  int i = blockIdx.x, tid = threadIdx.x;
  float acc = 0.f;
  for (int j8 = tid * 8; j8 < N; j8 += 256 * 8) {
    uint4 kv4 = *(const uint4*)(Kb + (size_t)i * N + j8);
    float4 va = *(const float4*)(v + j8);
    float4 vb = *(const float4*)(v + j8 + 4);
    unsigned int u;
    u = kv4.x;
    acc += __uint_as_float(u << 16) * va.x + __uint_as_float(u & 0xffff0000u) * va.y;
    u = kv4.y;
    acc += __uint_as_float(u << 16) * va.z + __uint_as_float(u & 0xffff0000u) * va.w;
    u = kv4.z;
    acc += __uint_as_float(u << 16) * vb.x + __uint_as_float(u & 0xffff0000u) * vb.y;
    u = kv4.w;
    acc += __uint_as_float(u << 16) * vb.z + __uint_as_float(u & 0xffff0000u) * vb.w;
  }
  float tot = blk_reduce_sum(acc, red);
  if (tid == 0) dv[i] = tot + 1e-5f;
}

// dst[c][r] = bf16(src[r][c]); src [R][C] f32, dst [C][R] bf16 (for f_w^T)
__global__ __launch_bounds__(256) void k_tcvt(
    const float* __restrict__ src, unsigned short* __restrict__ dst,
    int R, int C) {
  __shared__ unsigned short tile[32][33];
  int tx = threadIdx.x & 31, ty = threadIdx.x >> 5;
  int r0 = blockIdx.y * 32, c0 = blockIdx.x * 32;
#pragma unroll
  for (int i = 0; i < 4; ++i) {
    int r = r0 + ty + i * 8;
    tile[ty + i * 8][tx] = f2bf(src[(size_t)r * C + c0 + tx]);
  }
  __syncthreads();
#pragma unroll
  for (int i = 0; i < 4; ++i) {
    int cc = c0 + ty + i * 8;
    dst[(size_t)cc * R + r0 + tx] = tile[tx][ty + i * 8];
  }
}

// T[M][N] = x[M][K](f32->bf16) @ Bt[N][K]^T (bf16) + bias[N]
// Epilogue also writes Ttb[col][row] = bf16(v[row] * T[row][col]).
__global__ __launch_bounds__(256) void k_gemm1(
    const float* __restrict__ x, const unsigned short* __restrict__ Bt,
    const float* __restrict__ bias, const float* __restrict__ v,
    float* __restrict__ T, unsigned short* __restrict__ Ttb,
    int M, int N, int K) {
  __shared__ unsigned short As[64][72];
  __shared__ unsigned short Bs[64][72];
  int tid = threadIdx.x;
  int w = tid >> 6, l = tid & 63;
  int ln = l & 15, quad = l >> 4;
  int mh = (w & 1) * 32, nh = (w >> 1) * 32;
  int row0 = blockIdx.y * 64, col0 = blockIdx.x * 64;
  int lr = tid >> 3, lc = (tid & 7) * 8;
  f32x4 acc[2][2] = {};
  for (int k0 = 0; k0 < K; k0 += 64) {
    float4 a00 = *(const float4*)(x + (size_t)(row0 + lr) * K + k0 + lc);
    float4 a01 = *(const float4*)(x + (size_t)(row0 + lr) * K + k0 + lc + 4);
    float4 a10 = *(const float4*)(x + (size_t)(row0 + lr + 32) * K + k0 + lc);
    float4 a11 = *(const float4*)(x + (size_t)(row0 + lr + 32) * K + k0 + lc + 4);
    uint4 b0 = *(const uint4*)(Bt + (size_t)(col0 + lr) * K + k0 + lc);
    uint4 b1 = *(const uint4*)(Bt + (size_t)(col0 + lr + 32) * K + k0 + lc);
    __syncthreads();
    *(uint4*)&As[lr][lc] =
        make_uint4(pack2(a00.x, a00.y), pack2(a00.z, a00.w),
                   pack2(a01.x, a01.y), pack2(a01.z, a01.w));
    *(uint4*)&As[lr + 32][lc] =
        make_uint4(pack2(a10.x, a10.y), pack2(a10.z, a10.w),
                   pack2(a11.x, a11.y), pack2(a11.z, a11.w));
    *(uint4*)&Bs[lr][lc] = b0;
    *(uint4*)&Bs[lr + 32][lc] = b1;
    __syncthreads();
#pragma unroll
    for (int ks = 0; ks < 2; ++ks) {
      bf16x8 bfr[2], afr[2];
#pragma unroll
      for (int nt = 0; nt < 2; ++nt)
        bfr[nt] = *(const bf16x8*)&Bs[nh + nt * 16 + ln][ks * 32 + quad * 8];
#pragma unroll
      for (int mt = 0; mt < 2; ++mt)
        afr[mt] = *(const bf16x8*)&As[mh + mt * 16 + ln][ks * 32 + quad * 8];
#pragma unroll
      for (int mt = 0; mt < 2; ++mt)
#pragma unroll
        for (int nt = 0; nt < 2; ++nt)
          acc[mt][nt] = __builtin_amdgcn_mfma_f32_16x16x32_bf16(
              afr[mt], bfr[nt], acc[mt][nt], 0, 0, 0);
    }
  }
#pragma unroll
  for (int mt = 0; mt < 2; ++mt)
#pragma unroll
    for (int nt = 0; nt < 2; ++nt) {
      int col = col0 + nh + nt * 16 + ln;
      float bv = bias[col];
#pragma unroll
      for (int r = 0; r < 4; ++r) {
        int row = row0 + mh + mt * 16 + quad * 4 + r;
        float tv = acc[mt][nt][r] + bv;
        T[(size_t)row * N + col] = tv;
        Ttb[(size_t)col * M + row] = f2bf(v[row] * tv);
      }
    }
}

// acc = Kb[M][K] @ Ttb[N][K]^T (both bf16); epilogue:
// out = ALPHA*x + (1-ALPHA)*(1-2dt)*T + ((1-ALPHA)*2dt/EPS)/dv[row] * acc
__global__ __launch_bounds__(256) void k_gemm2(
    const unsigned short* __restrict__ A, const unsigned short* __restrict__ Bt,
    const float* __restrict__ x, const float* __restrict__ T,
    const float* __restrict__ dv, const float* __restrict__ dtp,
    float* __restrict__ out, int M, int N, int K) {
  __shared__ unsigned short As[64][72];
  __shared__ unsigned short Bs[64][72];
  int tid = threadIdx.x;
  int w = tid >> 6, l = tid & 63;
  int ln = l & 15, quad = l >> 4;
  int mh = (w & 1) * 32, nh = (w >> 1) * 32;
  int row0 = blockIdx.y * 64, col0 = blockIdx.x * 64;
  int lr = tid >> 3, lc = (tid & 7) * 8;
  f32x4 acc[2][2] = {};
  for (int k0 = 0; k0 < K; k0 += 64) {
    uint4 a0 = *(const uint4*)(A + (size_t)(row0 + lr) * K + k0 + lc);
    uint4 a1 = *(const uint4*)(A + (size_t)(row0 + lr + 32) * K + k0 + lc);
    uint4 b0 = *(const uint4*)(Bt + (size_t)(col0 + lr) * K + k0 + lc);
    uint4 b1 = *(const uint4*)(Bt + (size_t)(col0 + lr + 32) * K + k0 + lc);
    __syncthreads();
    *(uint4*)&As[lr][lc] = a0;
    *(uint4*)&As[lr + 32][lc] = a1;
    *(uint4*)&Bs[lr][lc] = b0;
    *(uint4*)&Bs[lr + 32][lc] = b1;
    __syncthreads();
#pragma unroll
    for (int ks = 0; ks < 2; ++ks) {
      bf16x8 bfr[2], afr[2];
#pragma unroll
      for (int nt = 0; nt < 2; ++nt)
        bfr[nt] = *(const bf16x8*)&Bs[nh + nt * 16 + ln][ks * 32 + quad * 8];
#pragma unroll
      for (int mt = 0; mt < 2; ++mt)
        afr[mt] = *(const bf16x8*)&As[mh + mt * 16 + ln][ks * 32 + quad * 8];
#pragma unroll
      for (int mt = 0; mt < 2; ++mt)
#pragma unroll
        for (int nt = 0; nt < 2; ++nt)
          acc[mt][nt] = __builtin_amdgcn_mfma_f32_16x16x32_bf16(
              afr[mt], bfr[nt], acc[mt][nt], 0, 0, 0);
    }
  }
  float dtv = dtp[0];
  float c2 = (1.f - ALPHA) * (1.f - 2.f * dtv);
  float c3b = (1.f - ALPHA) * 2.f * dtv / EPSILON;
#pragma unroll
  for (int mt = 0; mt < 2; ++mt)
#pragma unroll
    for (int nt = 0; nt < 2; ++nt) {
      int col = col0 + nh + nt * 16 + ln;
#pragma unroll
      for (int r = 0; r < 4; ++r) {
        int row = row0 + mh + mt * 16 + quad * 4 + r;
        size_t idx = (size_t)row * N + col;
        float c3 = c3b / dv[row];
        out[idx] = ALPHA * x[idx] + c2 * T[idx] + c3 * acc[mt][nt][r];
      }
    }
}

// In-place LayerNorm over rows of out (D elements, D/256 <= 4)
__global__ __launch_bounds__(256) void k_ln_rows(
    float* __restrict__ out, const float* __restrict__ g,
    const float* __restrict__ b, int D) {
  __shared__ float red[4];
  int i = blockIdx.x, tid = threadIdx.x;
  float v[4];
  int nt = D / 256;
  float sum = 0.f;
  for (int t = 0; t < nt; ++t) {
    v[t] = out[(size_t)i * D + tid + t * 256];
    sum += v[t];
  }
  float mu = blk_reduce_sum(sum, red) / (float)D;
  float sq = 0.f;
  for (int t = 0; t < nt; ++t) { float d2 = v[t] - mu; sq += d2 * d2; }
  float var = blk_reduce_sum(sq, red) / (float)D;
  float rs = rsqrtf(var + LN_EPS);
  for (int t = 0; t < nt; ++t) {
    int d0 = tid + t * 256;
    out[(size_t)i * D + d0] = (v[t] - mu) * rs * g[d0] + b[d0];
  }
}

extern "C" void kernel_launch(void* const* d_in, const int* in_sizes, int n_in,
                              void* d_out, int out_size, void* d_ws, size_t ws_size,
                              hipStream_t stream) {
  const float* x = (const float*)d_in[0];
  const float* proj_w = (const float*)d_in[1];
  const float* proj_b = (const float*)d_in[2];
  const float* ln1_g = (const float*)d_in[3];
  const float* ln1_b = (const float*)d_in[4];
  const float* pi_w1 = (const float*)d_in[5];
  const float* pi_b1 = (const float*)d_in[6];
  const float* pi_w2 = (const float*)d_in[7];
  const float* pi_b2 = (const float*)d_in[8];
  const float* dt = (const float*)d_in[9];
  const float* f_w = (const float*)d_in[10];
  const float* f_b = (const float*)d_in[11];
  const float* ln2_g = (const float*)d_in[12];
  const float* ln2_b = (const float*)d_in[13];
  float* out = (float*)d_out;

  int D = in_sizes[11];      // 768
  int N = in_sizes[0] / D;   // 2048

  unsigned short* Kb = (unsigned short*)d_ws;                  // N*N bf16
  float* T = (float*)(Kb + (size_t)N * N);                     // N*D f32
  unsigned short* Ttb = (unsigned short*)(T + (size_t)N * D);  // D*N bf16
  unsigned short* fwTb = Ttb + (size_t)D * N;                  // D*D bf16
  float* xp = (float*)(fwTb + (size_t)D * D);                  // N*16
  float* s = xp + (size_t)N * 16;                              // N
  float* pi = s + N;                                           // N
  float* q = pi + N;                                           // N
  float* v = q + N;                                            // N
  float* dv = v + N;                                           // N

  k_proj<<<N / 16, 256, 0, stream>>>(x, proj_w, proj_b, ln1_g, ln1_b, pi_w1,
                                     pi_b1, pi_w2, pi_b2, xp, s, pi, N, D);
  k_keps<<<N / 4, 256, 0, stream>>>(xp, s, pi, Kb, q, v, N);
  k_scale_bf<<<N, 256, 0, stream>>>(Kb, v, dv, N);
  k_tcvt<<<dim3(D / 32, D / 32), 256, 0, stream>>>(f_w, fwTb, D, D);
  k_gemm1<<<dim3(D / 64, N / 64), 256, 0, stream>>>(x, fwTb, f_b, v, T, Ttb,
                                                    N, D, D);
  k_gemm2<<<dim3(D / 64, N / 64), 256, 0, stream>>>(Kb, Ttb, x, T, dv, dt, out,
                                                    N, D, N);
  k_ln_rows<<<N, 256, 0, stream>>>(out, ln2_g, ln2_b, D);
}

// Round 4
// 165.297 us; speedup vs baseline: 2.0935x; 1.0142x over previous
//
#include <hip/hip_runtime.h>
#include <math.h>

#define EPSILON 0.3f
#define ALPHA 0.7f
#define LN_EPS 1e-5f

typedef __bf16 bf16x8 __attribute__((ext_vector_type(8)));
typedef float f32x4 __attribute__((ext_vector_type(4)));

__device__ __forceinline__ unsigned short f2bf(float f) {
  unsigned int u = __float_as_uint(f);
  return (unsigned short)((u + 0x7fffu + ((u >> 16) & 1u)) >> 16);
}
__device__ __forceinline__ float bf2f(unsigned short h) {
  return __uint_as_float(((unsigned int)h) << 16);
}
__device__ __forceinline__ unsigned int pack2(float lo, float hi) {
  return (unsigned int)f2bf(lo) | ((unsigned int)f2bf(hi) << 16);
}

__device__ __forceinline__ float wave_reduce(float v) {
#pragma unroll
  for (int off = 32; off > 0; off >>= 1) v += __shfl_xor(v, off, 64);
  return v;
}

__device__ __forceinline__ float blk_reduce_sum(float v, float* red) {
  v = wave_reduce(v);
  int lane = threadIdx.x & 63, wid = threadIdx.x >> 6;
  __syncthreads();
  if (lane == 0) red[wid] = v;
  __syncthreads();
  float s = 0.f;
  int nw = (blockDim.x + 63) >> 6;
  for (int w = 0; w < nw; ++w) s += red[w];
  return s;
}

// 16 rows per block. proj -> LN -> ReLU -> xp, s ; pi head with register weights.
// Assumes D == 768 (3 chunks of 256), L == 16.
__global__ __launch_bounds__(256) void k_proj(
    const float* __restrict__ x, const float* __restrict__ proj_w,
    const float* __restrict__ proj_b, const float* __restrict__ ln1_g,
    const float* __restrict__ ln1_b, const float* __restrict__ pi_w1,
    const float* __restrict__ pi_b1, const float* __restrict__ pi_w2,
    const float* __restrict__ pi_b2, float* __restrict__ xp,
    float* __restrict__ s, float* __restrict__ pi, int N, int D) {
  __shared__ float xs[16][68];
  __shared__ float ws[64][20];
  __shared__ float ysh[16][17];
  __shared__ float xps[16][16];
  __shared__ float pr[16][4];
  int tid = threadIdx.x;
  int row0 = blockIdx.x * 16;
  int row = tid >> 4, l = tid & 15;
  int lane = tid & 63, w = tid >> 6;
  int skc = (tid & 15) * 4;
  int wk = tid >> 2, wl = (tid & 3) * 4;
  float acc = 0.f;
  for (int k0 = 0; k0 < D; k0 += 64) {
    float4 xv = *(const float4*)(x + (size_t)(row0 + row) * D + k0 + skc);
    float4 wv = *(const float4*)(proj_w + (size_t)(k0 + wk) * 16 + wl);
    __syncthreads();
    *(float4*)&xs[row][skc] = xv;
    *(float4*)&ws[wk][wl] = wv;
    __syncthreads();
#pragma unroll
    for (int kk = 0; kk < 64; kk += 4) {
      float4 a4 = *(const float4*)&xs[row][kk];
      acc += a4.x * ws[kk + 0][l];
      acc += a4.y * ws[kk + 1][l];
      acc += a4.z * ws[kk + 2][l];
      acc += a4.w * ws[kk + 3][l];
    }
  }
  float y = acc + proj_b[l];
  ysh[row][l] = y;
  __syncthreads();
  float mu = 0.f;
#pragma unroll
  for (int t = 0; t < 16; ++t) mu += ysh[row][t];
  mu *= (1.f / 16.f);
  float var = 0.f;
#pragma unroll
  for (int t = 0; t < 16; ++t) { float d2 = ysh[row][t] - mu; var += d2 * d2; }
  var *= (1.f / 16.f);
  float rstd = rsqrtf(var + LN_EPS);
  float xpv = fmaxf((y - mu) * rstd * ln1_g[l] + ln1_b[l], 0.f);
  xps[row][l] = xpv;
  xp[(size_t)(row0 + row) * 16 + l] = xpv;
  float sq = xpv * xpv;
  sq += __shfl_xor(sq, 8, 64);
  sq += __shfl_xor(sq, 4, 64);
  sq += __shfl_xor(sq, 2, 64);
  sq += __shfl_xor(sq, 1, 64);
  if ((lane & 15) == 0) s[row0 + row] = sq;
  __syncthreads();
  float w1r[3][16], b1r[3], w2r[3];
#pragma unroll
  for (int c = 0; c < 3; ++c) {
    int d0 = tid + c * 256;
    b1r[c] = pi_b1[d0];
    w2r[c] = pi_w2[d0];
#pragma unroll
    for (int t = 0; t < 16; ++t) w1r[c][t] = pi_w1[(size_t)t * D + d0];
  }
  float pacc[16];
#pragma unroll
  for (int r = 0; r < 16; ++r) pacc[r] = 0.f;
#pragma unroll
  for (int r = 0; r < 16; ++r) {
    float xv[16];
#pragma unroll
    for (int t4 = 0; t4 < 4; ++t4) {
      float4 xq = *(const float4*)&xps[r][t4 * 4];
      xv[t4 * 4 + 0] = xq.x; xv[t4 * 4 + 1] = xq.y;
      xv[t4 * 4 + 2] = xq.z; xv[t4 * 4 + 3] = xq.w;
    }
    float pa = 0.f;
#pragma unroll
    for (int c = 0; c < 3; ++c) {
      float h = b1r[c];
#pragma unroll
      for (int t = 0; t < 16; ++t) h += xv[t] * w1r[c][t];
      h = fmaxf(h, 0.f);
      pa += h * w2r[c];
    }
    pacc[r] = pa;
  }
#pragma unroll
  for (int r = 0; r < 16; ++r) {
    float pv = wave_reduce(pacc[r]);
    if (lane == 0) pr[r][w] = pv;
  }
  __syncthreads();
  if (tid < 16) {
    float tot = pr[tid][0] + pr[tid][1] + pr[tid][2] + pr[tid][3] + pi_b2[0];
    pi[row0 + tid] = 1.f / (1.f + expf(-tot));
  }
}

// 4 rows per block, 2 cols per thread; writes Kb bf16 (4B stores), q, v.
__global__ __launch_bounds__(256) void k_keps(
    const float* __restrict__ xp, const float* __restrict__ s,
    const float* __restrict__ pi, unsigned short* __restrict__ Kb,
    float* __restrict__ q, float* __restrict__ v, int N) {
  __shared__ float qs[4][4];
  int i0 = blockIdx.x * 4;
  int tid = threadIdx.x, lane = tid & 63, w = tid >> 6;
  float a[4][16], si[4];
#pragma unroll
  for (int r = 0; r < 4; ++r) {
    const float* ap = xp + (size_t)(i0 + r) * 16;
#pragma unroll
    for (int t = 0; t < 16; ++t) a[r][t] = ap[t];
    si[r] = s[i0 + r];
  }
  const float c = 1.f / (4.f * EPSILON);
  float qa[4] = {0.f, 0.f, 0.f, 0.f};
  for (int it = 0; it < N / 512; ++it) {
    int j = it * 512 + tid * 2;
    const float4* bp = (const float4*)(xp + (size_t)j * 16);
    float4 b0 = bp[0], b1 = bp[1], b2 = bp[2], b3 = bp[3];
    float4 c0 = bp[4], c1 = bp[5], c2 = bp[6], c3 = bp[7];
    float bv[16] = {b0.x, b0.y, b0.z, b0.w, b1.x, b1.y, b1.z, b1.w,
                    b2.x, b2.y, b2.z, b2.w, b3.x, b3.y, b3.z, b3.w};
    float cv[16] = {c0.x, c0.y, c0.z, c0.w, c1.x, c1.y, c1.z, c1.w,
                    c2.x, c2.y, c2.z, c2.w, c3.x, c3.y, c3.z, c3.w};
    float sj0 = s[j], sj1 = s[j + 1];
#pragma unroll
    for (int r = 0; r < 4; ++r) {
      float d0 = 0.f, d1 = 0.f;
#pragma unroll
      for (int t = 0; t < 16; ++t) { d0 += a[r][t] * bv[t]; d1 += a[r][t] * cv[t]; }
      float k0 = expf(-c * (si[r] + sj0 - 2.f * d0));
      float k1 = expf(-c * (si[r] + sj1 - 2.f * d1));
      *(unsigned int*)(Kb + (size_t)(i0 + r) * N + j) = pack2(k0, k1);
      qa[r] += k0 + k1;
    }
  }
#pragma unroll
  for (int r = 0; r < 4; ++r) {
    float t = wave_reduce(qa[r]);
    if (lane == 0) qs[r][w] = t;
  }
  __syncthreads();
  if (tid < 4) {
    float tot = qs[tid][0] + qs[tid][1] + qs[tid][2] + qs[tid][3];
    q[i0 + tid] = tot;
    v[i0 + tid] = pi[i0 + tid] / tot;
  }
}

// dv[i] = sum_j bf16K[i][j]*v[j] + 1e-5
__global__ __launch_bounds__(256) void k_scale_bf(
    const unsigned short* __restrict__ Kb, const float* __restrict__ v,
    float* __restrict__ dv, int N) {
  __shared__ float red[4];
  int i = blockIdx.x, tid = threadIdx.x;
  float acc = 0.f;
  for (int j8 = tid * 8; j8 < N; j8 += 256 * 8) {
    uint4 kv4 = *(const uint4*)(Kb + (size_t)i * N + j8);
    float4 va = *(const float4*)(v + j8);
    float4 vb = *(const float4*)(v + j8 + 4);
    unsigned int u;
    u = kv4.x;
    acc += __uint_as_float(u << 16) * va.x + __uint_as_float(u & 0xffff0000u) * va.y;
    u = kv4.y;
    acc += __uint_as_float(u << 16) * va.z + __uint_as_float(u & 0xffff0000u) * va.w;
    u = kv4.z;
    acc += __uint_as_float(u << 16) * vb.x + __uint_as_float(u & 0xffff0000u) * vb.y;
    u = kv4.w;
    acc += __uint_as_float(u << 16) * vb.z + __uint_as_float(u & 0xffff0000u) * vb.w;
  }
  float tot = blk_reduce_sum(acc, red);
  if (tid == 0) dv[i] = tot + 1e-5f;
}

// dst[c][r] = bf16(src[r][c]); for f_w^T
__global__ __launch_bounds__(256) void k_tcvt(
    const float* __restrict__ src, unsigned short* __restrict__ dst,
    int R, int C) {
  __shared__ unsigned short tile[32][33];
  int tx = threadIdx.x & 31, ty = threadIdx.x >> 5;
  int r0 = blockIdx.y * 32, c0 = blockIdx.x * 32;
#pragma unroll
  for (int i = 0; i < 4; ++i) {
    int r = r0 + ty + i * 8;
    tile[ty + i * 8][tx] = f2bf(src[(size_t)r * C + c0 + tx]);
  }
  __syncthreads();
#pragma unroll
  for (int i = 0; i < 4; ++i) {
    int cc = c0 + ty + i * 8;
    dst[(size_t)cc * R + r0 + tx] = tile[tx][ty + i * 8];
  }
}

// Split-K GEMM1 partial: P[s][row][col] = x[row][ks..ke) @ fwTb[col][ks..ke)
__global__ __launch_bounds__(256) void k_gemm1(
    const float* __restrict__ x, const unsigned short* __restrict__ Bt,
    float* __restrict__ P, int M, int N, int K, int klen) {
  __shared__ unsigned short As[64][72];
  __shared__ unsigned short Bs[64][72];
  int tid = threadIdx.x;
  int w = tid >> 6, l = tid & 63;
  int ln = l & 15, quad = l >> 4;
  int mh = (w & 1) * 32, nh = (w >> 1) * 32;
  int row0 = blockIdx.y * 64, col0 = blockIdx.x * 64;
  int ks = blockIdx.z * klen;
  int lr = tid >> 3, lc = (tid & 7) * 8;
  f32x4 acc[2][2] = {};
  for (int k0 = ks; k0 < ks + klen; k0 += 64) {
    float4 a00 = *(const float4*)(x + (size_t)(row0 + lr) * K + k0 + lc);
    float4 a01 = *(const float4*)(x + (size_t)(row0 + lr) * K + k0 + lc + 4);
    float4 a10 = *(const float4*)(x + (size_t)(row0 + lr + 32) * K + k0 + lc);
    float4 a11 = *(const float4*)(x + (size_t)(row0 + lr + 32) * K + k0 + lc + 4);
    uint4 b0 = *(const uint4*)(Bt + (size_t)(col0 + lr) * K + k0 + lc);
    uint4 b1 = *(const uint4*)(Bt + (size_t)(col0 + lr + 32) * K + k0 + lc);
    __syncthreads();
    *(uint4*)&As[lr][lc] =
        make_uint4(pack2(a00.x, a00.y), pack2(a00.z, a00.w),
                   pack2(a01.x, a01.y), pack2(a01.z, a01.w));
    *(uint4*)&As[lr + 32][lc] =
        make_uint4(pack2(a10.x, a10.y), pack2(a10.z, a10.w),
                   pack2(a11.x, a11.y), pack2(a11.z, a11.w));
    *(uint4*)&Bs[lr][lc] = b0;
    *(uint4*)&Bs[lr + 32][lc] = b1;
    __syncthreads();
#pragma unroll
    for (int kss = 0; kss < 2; ++kss) {
      bf16x8 bfr[2], afr[2];
#pragma unroll
      for (int nt = 0; nt < 2; ++nt)
        bfr[nt] = *(const bf16x8*)&Bs[nh + nt * 16 + ln][kss * 32 + quad * 8];
#pragma unroll
      for (int mt = 0; mt < 2; ++mt)
        afr[mt] = *(const bf16x8*)&As[mh + mt * 16 + ln][kss * 32 + quad * 8];
#pragma unroll
      for (int mt = 0; mt < 2; ++mt)
#pragma unroll
        for (int nt = 0; nt < 2; ++nt)
          acc[mt][nt] = __builtin_amdgcn_mfma_f32_16x16x32_bf16(
              afr[mt], bfr[nt], acc[mt][nt], 0, 0, 0);
    }
  }
  float* Ps = P + (size_t)blockIdx.z * M * N;
#pragma unroll
  for (int mt = 0; mt < 2; ++mt)
#pragma unroll
    for (int nt = 0; nt < 2; ++nt) {
      int col = col0 + nh + nt * 16 + ln;
#pragma unroll
      for (int r = 0; r < 4; ++r) {
        int row = row0 + mh + mt * 16 + quad * 4 + r;
        Ps[(size_t)row * N + col] = acc[mt][nt][r];
      }
    }
}

// T = P0+P1+bias ; Ttb[c][r] = bf16(v[r]*T[r][c]) (LDS transpose)
__global__ __launch_bounds__(256) void k_red1(
    const float* __restrict__ P, const float* __restrict__ bias,
    const float* __restrict__ v, float* __restrict__ T,
    unsigned short* __restrict__ Ttb, int M, int N) {
  __shared__ unsigned short tile[32][33];
  int tx = threadIdx.x & 31, ty = threadIdx.x >> 5;
  int r0 = blockIdx.y * 32, c0 = blockIdx.x * 32;
  const float* P1 = P + (size_t)M * N;
  float bv = bias[c0 + tx];
#pragma unroll
  for (int i = 0; i < 4; ++i) {
    int r = r0 + ty + i * 8;
    size_t idx = (size_t)r * N + c0 + tx;
    float tv = P[idx] + P1[idx] + bv;
    T[idx] = tv;
    tile[ty + i * 8][tx] = f2bf(v[r] * tv);
  }
  __syncthreads();
#pragma unroll
  for (int i = 0; i < 4; ++i) {
    int cc = c0 + ty + i * 8;
    Ttb[(size_t)cc * M + r0 + tx] = tile[tx][ty + i * 8];
  }
}

// Split-K GEMM2 partial: Q[s][row][col] = Kb[row][ks..ke) @ Ttb[col][ks..ke)
__global__ __launch_bounds__(256) void k_gemm2(
    const unsigned short* __restrict__ A, const unsigned short* __restrict__ Bt,
    float* __restrict__ Q, int M, int N, int K, int klen) {
  __shared__ unsigned short As[64][72];
  __shared__ unsigned short Bs[64][72];
  int tid = threadIdx.x;
  int w = tid >> 6, l = tid & 63;
  int ln = l & 15, quad = l >> 4;
  int mh = (w & 1) * 32, nh = (w >> 1) * 32;
  int row0 = blockIdx.y * 64, col0 = blockIdx.x * 64;
  int ks = blockIdx.z * klen;
  int lr = tid >> 3, lc = (tid & 7) * 8;
  f32x4 acc[2][2] = {};
  for (int k0 = ks; k0 < ks + klen; k0 += 64) {
    uint4 a0 = *(const uint4*)(A + (size_t)(row0 + lr) * K + k0 + lc);
    uint4 a1 = *(const uint4*)(A + (size_t)(row0 + lr + 32) * K + k0 + lc);
    uint4 b0 = *(const uint4*)(Bt + (size_t)(col0 + lr) * K + k0 + lc);
    uint4 b1 = *(const uint4*)(Bt + (size_t)(col0 + lr + 32) * K + k0 + lc);
    __syncthreads();
    *(uint4*)&As[lr][lc] = a0;
    *(uint4*)&As[lr + 32][lc] = a1;
    *(uint4*)&Bs[lr][lc] = b0;
    *(uint4*)&Bs[lr + 32][lc] = b1;
    __syncthreads();
#pragma unroll
    for (int kss = 0; kss < 2; ++kss) {
      bf16x8 bfr[2], afr[2];
#pragma unroll
      for (int nt = 0; nt < 2; ++nt)
        bfr[nt] = *(const bf16x8*)&Bs[nh + nt * 16 + ln][kss * 32 + quad * 8];
#pragma unroll
      for (int mt = 0; mt < 2; ++mt)
        afr[mt] = *(const bf16x8*)&As[mh + mt * 16 + ln][kss * 32 + quad * 8];
#pragma unroll
      for (int mt = 0; mt < 2; ++mt)
#pragma unroll
        for (int nt = 0; nt < 2; ++nt)
          acc[mt][nt] = __builtin_amdgcn_mfma_f32_16x16x32_bf16(
              afr[mt], bfr[nt], acc[mt][nt], 0, 0, 0);
    }
  }
  float* Qs = Q + (size_t)blockIdx.z * M * N;
#pragma unroll
  for (int mt = 0; mt < 2; ++mt)
#pragma unroll
    for (int nt = 0; nt < 2; ++nt) {
      int col = col0 + nh + nt * 16 + ln;
#pragma unroll
      for (int r = 0; r < 4; ++r) {
        int row = row0 + mh + mt * 16 + quad * 4 + r;
        Qs[(size_t)row * N + col] = acc[mt][nt][r];
      }
    }
}

// Per row: acc=Q0+Q1+Q2+Q3; pre = ALPHA*x + c2*T + c3/dv*acc; out = LN(pre)
__global__ __launch_bounds__(256) void k_red2_ln(
    const float* __restrict__ Q, const float* __restrict__ x,
    const float* __restrict__ T, const float* __restrict__ dv,
    const float* __restrict__ dtp, const float* __restrict__ g,
    const float* __restrict__ b, float* __restrict__ out, int D, size_t MN) {
  __shared__ float red[4];
  int i = blockIdx.x, tid = threadIdx.x;
  float dtv = dtp[0];
  float c2 = (1.f - ALPHA) * (1.f - 2.f * dtv);
  float c3 = (1.f - ALPHA) * 2.f * dtv / EPSILON / dv[i];
  float vv[4];
  int nt = D / 256;
  float sum = 0.f;
  for (int t = 0; t < nt; ++t) {
    size_t idx = (size_t)i * D + tid + t * 256;
    float acc = Q[idx] + Q[idx + MN] + Q[idx + 2 * MN] + Q[idx + 3 * MN];
    float val = ALPHA * x[idx] + c2 * T[idx] + c3 * acc;
    vv[t] = val;
    sum += val;
  }
  float mu = blk_reduce_sum(sum, red) / (float)D;
  float sq = 0.f;
  for (int t = 0; t < nt; ++t) { float d2 = vv[t] - mu; sq += d2 * d2; }
  float var = blk_reduce_sum(sq, red) / (float)D;
  float rs = rsqrtf(var + LN_EPS);
  for (int t = 0; t < nt; ++t) {
    int d0 = tid + t * 256;
    out[(size_t)i * D + d0] = (vv[t] - mu) * rs * g[d0] + b[d0];
  }
}

extern "C" void kernel_launch(void* const* d_in, const int* in_sizes, int n_in,
                              void* d_out, int out_size, void* d_ws, size_t ws_size,
                              hipStream_t stream) {
  const float* x = (const float*)d_in[0];
  const float* proj_w = (const float*)d_in[1];
  const float* proj_b = (const float*)d_in[2];
  const float* ln1_g = (const float*)d_in[3];
  const float* ln1_b = (const float*)d_in[4];
  const float* pi_w1 = (const float*)d_in[5];
  const float* pi_b1 = (const float*)d_in[6];
  const float* pi_w2 = (const float*)d_in[7];
  const float* pi_b2 = (const float*)d_in[8];
  const float* dt = (const float*)d_in[9];
  const float* f_w = (const float*)d_in[10];
  const float* f_b = (const float*)d_in[11];
  const float* ln2_g = (const float*)d_in[12];
  const float* ln2_b = (const float*)d_in[13];
  float* out = (float*)d_out;

  int D = in_sizes[11];      // 768
  int N = in_sizes[0] / D;   // 2048

  unsigned short* Kb = (unsigned short*)d_ws;                  // N*N bf16
  float* T = (float*)(Kb + (size_t)N * N);                     // N*D f32
  unsigned short* Ttb = (unsigned short*)(T + (size_t)N * D);  // D*N bf16
  unsigned short* fwTb = Ttb + (size_t)D * N;                  // D*D bf16
  float* P = (float*)(fwTb + (size_t)D * D);                   // 2*N*D f32
  float* Q = P + (size_t)2 * N * D;                            // 4*N*D f32
  float* xp = Q + (size_t)4 * N * D;                           // N*16
  float* s = xp + (size_t)N * 16;                              // N
  float* pi = s + N;                                           // N
  float* q = pi + N;                                           // N
  float* v = q + N;                                            // N
  float* dv = v + N;                                           // N

  k_proj<<<N / 16, 256, 0, stream>>>(x, proj_w, proj_b, ln1_g, ln1_b, pi_w1,
                                     pi_b1, pi_w2, pi_b2, xp, s, pi, N, D);
  k_keps<<<N / 4, 256, 0, stream>>>(xp, s, pi, Kb, q, v, N);
  k_scale_bf<<<N, 256, 0, stream>>>(Kb, v, dv, N);
  k_tcvt<<<dim3(D / 32, D / 32), 256, 0, stream>>>(f_w, fwTb, D, D);
  k_gemm1<<<dim3(D / 64, N / 64, 2), 256, 0, stream>>>(x, fwTb, P, N, D, D,
                                                       D / 2);
  k_red1<<<dim3(D / 32, N / 32), 256, 0, stream>>>(P, f_b, v, T, Ttb, N, D);
  k_gemm2<<<dim3(D / 64, N / 64, 4), 256, 0, stream>>>(Kb, Ttb, Q, N, D, N,
                                                       N / 4);
  k_red2_ln<<<N, 256, 0, stream>>>(Q, x, T, dv, dt, ln2_g, ln2_b, out, D,
                                   (size_t)N * D);
}

// Round 5
// 161.440 us; speedup vs baseline: 2.1435x; 1.0239x over previous
//
#include <hip/hip_runtime.h>
#include <math.h>

#define EPSILON 0.3f
#define ALPHA 0.7f
#define LN_EPS 1e-5f

typedef __bf16 bf16x8 __attribute__((ext_vector_type(8)));
typedef float f32x4 __attribute__((ext_vector_type(4)));

__device__ __forceinline__ unsigned short f2bf(float f) {
  unsigned int u = __float_as_uint(f);
  return (unsigned short)((u + 0x7fffu + ((u >> 16) & 1u)) >> 16);
}
__device__ __forceinline__ unsigned int pack2(float lo, float hi) {
  return (unsigned int)f2bf(lo) | ((unsigned int)f2bf(hi) << 16);
}

__device__ __forceinline__ float wave_reduce(float v) {
#pragma unroll
  for (int off = 32; off > 0; off >>= 1) v += __shfl_xor(v, off, 64);
  return v;
}

__device__ __forceinline__ float blk_reduce_sum(float v, float* red) {
  v = wave_reduce(v);
  int lane = threadIdx.x & 63, wid = threadIdx.x >> 6;
  __syncthreads();
  if (lane == 0) red[wid] = v;
  __syncthreads();
  float s = 0.f;
  int nw = (blockDim.x + 63) >> 6;
  for (int w = 0; w < nw; ++w) s += red[w];
  return s;
}

// 16 rows per block. proj -> LN -> ReLU -> xp, s ; pi head with register weights.
// Assumes D == 768, L == 16.
__global__ __launch_bounds__(256) void k_proj(
    const float* __restrict__ x, const float* __restrict__ proj_w,
    const float* __restrict__ proj_b, const float* __restrict__ ln1_g,
    const float* __restrict__ ln1_b, const float* __restrict__ pi_w1,
    const float* __restrict__ pi_b1, const float* __restrict__ pi_w2,
    const float* __restrict__ pi_b2, float* __restrict__ xp,
    float* __restrict__ s, float* __restrict__ pi, int N, int D) {
  __shared__ float xs[16][68];
  __shared__ float ws[64][20];
  __shared__ float ysh[16][17];
  __shared__ float xps[16][16];
  __shared__ float pr[16][4];
  int tid = threadIdx.x;
  int row0 = blockIdx.x * 16;
  int row = tid >> 4, l = tid & 15;
  int lane = tid & 63, w = tid >> 6;
  int skc = (tid & 15) * 4;
  int wk = tid >> 2, wl = (tid & 3) * 4;
  float acc = 0.f;
  for (int k0 = 0; k0 < D; k0 += 64) {
    float4 xv = *(const float4*)(x + (size_t)(row0 + row) * D + k0 + skc);
    float4 wv = *(const float4*)(proj_w + (size_t)(k0 + wk) * 16 + wl);
    __syncthreads();
    *(float4*)&xs[row][skc] = xv;
    *(float4*)&ws[wk][wl] = wv;
    __syncthreads();
#pragma unroll
    for (int kk = 0; kk < 64; kk += 4) {
      float4 a4 = *(const float4*)&xs[row][kk];
      acc += a4.x * ws[kk + 0][l];
      acc += a4.y * ws[kk + 1][l];
      acc += a4.z * ws[kk + 2][l];
      acc += a4.w * ws[kk + 3][l];
    }
  }
  float y = acc + proj_b[l];
  ysh[row][l] = y;
  __syncthreads();
  float mu = 0.f;
#pragma unroll
  for (int t = 0; t < 16; ++t) mu += ysh[row][t];
  mu *= (1.f / 16.f);
  float var = 0.f;
#pragma unroll
  for (int t = 0; t < 16; ++t) { float d2 = ysh[row][t] - mu; var += d2 * d2; }
  var *= (1.f / 16.f);
  float rstd = rsqrtf(var + LN_EPS);
  float xpv = fmaxf((y - mu) * rstd * ln1_g[l] + ln1_b[l], 0.f);
  xps[row][l] = xpv;
  xp[(size_t)(row0 + row) * 16 + l] = xpv;
  float sq = xpv * xpv;
  sq += __shfl_xor(sq, 8, 64);
  sq += __shfl_xor(sq, 4, 64);
  sq += __shfl_xor(sq, 2, 64);
  sq += __shfl_xor(sq, 1, 64);
  if ((lane & 15) == 0) s[row0 + row] = sq;
  __syncthreads();
  float w1r[3][16], b1r[3], w2r[3];
#pragma unroll
  for (int c = 0; c < 3; ++c) {
    int d0 = tid + c * 256;
    b1r[c] = pi_b1[d0];
    w2r[c] = pi_w2[d0];
#pragma unroll
    for (int t = 0; t < 16; ++t) w1r[c][t] = pi_w1[(size_t)t * D + d0];
  }
  float pacc[16];
#pragma unroll
  for (int r = 0; r < 16; ++r) pacc[r] = 0.f;
#pragma unroll
  for (int r = 0; r < 16; ++r) {
    float xv[16];
#pragma unroll
    for (int t4 = 0; t4 < 4; ++t4) {
      float4 xq = *(const float4*)&xps[r][t4 * 4];
      xv[t4 * 4 + 0] = xq.x; xv[t4 * 4 + 1] = xq.y;
      xv[t4 * 4 + 2] = xq.z; xv[t4 * 4 + 3] = xq.w;
    }
    float pa = 0.f;
#pragma unroll
    for (int c = 0; c < 3; ++c) {
      float h = b1r[c];
#pragma unroll
      for (int t = 0; t < 16; ++t) h += xv[t] * w1r[c][t];
      h = fmaxf(h, 0.f);
      pa += h * w2r[c];
    }
    pacc[r] = pa;
  }
#pragma unroll
  for (int r = 0; r < 16; ++r) {
    float pv = wave_reduce(pacc[r]);
    if (lane == 0) pr[r][w] = pv;
  }
  __syncthreads();
  if (tid < 16) {
    float tot = pr[tid][0] + pr[tid][1] + pr[tid][2] + pr[tid][3] + pi_b2[0];
    pi[row0 + tid] = 1.f / (1.f + expf(-tot));
  }
}

// 4 rows per block, 2 cols per thread; writes Kb bf16 (4B stores), q, v.
__global__ __launch_bounds__(256) void k_keps(
    const float* __restrict__ xp, const float* __restrict__ s,
    const float* __restrict__ pi, unsigned short* __restrict__ Kb,
    float* __restrict__ q, float* __restrict__ v, int N) {
  __shared__ float qs[4][4];
  int i0 = blockIdx.x * 4;
  int tid = threadIdx.x, lane = tid & 63, w = tid >> 6;
  float a[4][16], si[4];
#pragma unroll
  for (int r = 0; r < 4; ++r) {
    const float* ap = xp + (size_t)(i0 + r) * 16;
#pragma unroll
    for (int t = 0; t < 16; ++t) a[r][t] = ap[t];
    si[r] = s[i0 + r];
  }
  const float c = 1.f / (4.f * EPSILON);
  float qa[4] = {0.f, 0.f, 0.f, 0.f};
  for (int it = 0; it < N / 512; ++it) {
    int j = it * 512 + tid * 2;
    const float4* bp = (const float4*)(xp + (size_t)j * 16);
    float4 b0 = bp[0], b1 = bp[1], b2 = bp[2], b3 = bp[3];
    float4 c0 = bp[4], c1 = bp[5], c2 = bp[6], c3 = bp[7];
    float bv[16] = {b0.x, b0.y, b0.z, b0.w, b1.x, b1.y, b1.z, b1.w,
                    b2.x, b2.y, b2.z, b2.w, b3.x, b3.y, b3.z, b3.w};
    float cv[16] = {c0.x, c0.y, c0.z, c0.w, c1.x, c1.y, c1.z, c1.w,
                    c2.x, c2.y, c2.z, c2.w, c3.x, c3.y, c3.z, c3.w};
    float sj0 = s[j], sj1 = s[j + 1];
#pragma unroll
    for (int r = 0; r < 4; ++r) {
      float d0 = 0.f, d1 = 0.f;
#pragma unroll
      for (int t = 0; t < 16; ++t) { d0 += a[r][t] * bv[t]; d1 += a[r][t] * cv[t]; }
      float k0 = expf(-c * (si[r] + sj0 - 2.f * d0));
      float k1 = expf(-c * (si[r] + sj1 - 2.f * d1));
      *(unsigned int*)(Kb + (size_t)(i0 + r) * N + j) = pack2(k0, k1);
      qa[r] += k0 + k1;
    }
  }
#pragma unroll
  for (int r = 0; r < 4; ++r) {
    float t = wave_reduce(qa[r]);
    if (lane == 0) qs[r][w] = t;
  }
  __syncthreads();
  if (tid < 4) {
    float tot = qs[tid][0] + qs[tid][1] + qs[tid][2] + qs[tid][3];
    q[i0 + tid] = tot;
    v[i0 + tid] = pi[i0 + tid] / tot;
  }
}

// One launch, three phases by block range:
//   [0, N):            dv[i] = sum_j bf16(Kb[i][j])*v[j] + 1e-5
//   [N, N+xvtB):       xvbT[d][j] = bf16(v[j] * x[j][d])   (32x32 tile transpose)
//   [N+xvtB, +tcvtB):  fwTb[c][r] = bf16(f_w[r][c])
__global__ __launch_bounds__(256) void k_prep(
    const unsigned short* __restrict__ Kb, const float* __restrict__ v,
    float* __restrict__ dv, const float* __restrict__ x,
    unsigned short* __restrict__ xvbT, const float* __restrict__ fw,
    unsigned short* __restrict__ fwTb, int N, int D) {
  __shared__ float sh[544];
  int bid = blockIdx.x, tid = threadIdx.x;
  int xvtCols = D / 32;            // tiles along D
  int xvtB = xvtCols * (N / 32);
  if (bid < N) {
    int i = bid;
    float acc = 0.f;
    int j8 = tid * 8;
    for (; j8 < N; j8 += 256 * 8) {
      uint4 kv4 = *(const uint4*)(Kb + (size_t)i * N + j8);
      float4 va = *(const float4*)(v + j8);
      float4 vb = *(const float4*)(v + j8 + 4);
      unsigned int u;
      u = kv4.x;
      acc += __uint_as_float(u << 16) * va.x + __uint_as_float(u & 0xffff0000u) * va.y;
      u = kv4.y;
      acc += __uint_as_float(u << 16) * va.z + __uint_as_float(u & 0xffff0000u) * va.w;
      u = kv4.z;
      acc += __uint_as_float(u << 16) * vb.x + __uint_as_float(u & 0xffff0000u) * vb.y;
      u = kv4.w;
      acc += __uint_as_float(u << 16) * vb.z + __uint_as_float(u & 0xffff0000u) * vb.w;
    }
    float tot = blk_reduce_sum(acc, sh);
    if (tid == 0) dv[i] = tot + 1e-5f;
  } else if (bid < N + xvtB) {
    int t = bid - N;
    unsigned short (*tile)[33] = (unsigned short (*)[33])sh;
    int tx = tid & 31, ty = tid >> 5;
    int c0 = (t % xvtCols) * 32;   // over D
    int r0 = (t / xvtCols) * 32;   // over N
#pragma unroll
    for (int i = 0; i < 4; ++i) {
      int r = r0 + ty + i * 8;
      tile[ty + i * 8][tx] = f2bf(v[r] * x[(size_t)r * D + c0 + tx]);
    }
    __syncthreads();
#pragma unroll
    for (int i = 0; i < 4; ++i) {
      int cc = c0 + ty + i * 8;
      xvbT[(size_t)cc * N + r0 + tx] = tile[tx][ty + i * 8];
    }
  } else {
    int t = bid - N - xvtB;
    unsigned short (*tile)[33] = (unsigned short (*)[33])sh;
    int tx = tid & 31, ty = tid >> 5;
    int tcvtCols = D / 32;
    int c0 = (t % tcvtCols) * 32;
    int r0 = (t / tcvtCols) * 32;
#pragma unroll
    for (int i = 0; i < 4; ++i) {
      int r = r0 + ty + i * 8;
      tile[ty + i * 8][tx] = f2bf(fw[(size_t)r * D + c0 + tx]);
    }
    __syncthreads();
#pragma unroll
    for (int i = 0; i < 4; ++i) {
      int cc = c0 + ty + i * 8;
      fwTb[(size_t)cc * D + r0 + tx] = tile[tx][ty + i * 8];
    }
  }
}

// Y = Kb[M][K] @ xvbT[Ncols][K]^T, epilogue:
// Z[row][col] = bf16(c2*x[row][col] + (c3/dv[row])*acc)
__global__ __launch_bounds__(256) void k_gemmA(
    const unsigned short* __restrict__ A, const unsigned short* __restrict__ Bt,
    const float* __restrict__ x, const float* __restrict__ dv,
    const float* __restrict__ dtp, unsigned short* __restrict__ Z,
    int M, int N, int K) {
  __shared__ unsigned short As[64][72];
  __shared__ unsigned short Bs[64][72];
  int tid = threadIdx.x;
  int w = tid >> 6, l = tid & 63;
  int ln = l & 15, quad = l >> 4;
  int mh = (w & 1) * 32, nh = (w >> 1) * 32;
  int row0 = blockIdx.y * 64, col0 = blockIdx.x * 64;
  int lr = tid >> 3, lc = (tid & 7) * 8;
  f32x4 acc[2][2] = {};
  for (int k0 = 0; k0 < K; k0 += 64) {
    uint4 a0 = *(const uint4*)(A + (size_t)(row0 + lr) * K + k0 + lc);
    uint4 a1 = *(const uint4*)(A + (size_t)(row0 + lr + 32) * K + k0 + lc);
    uint4 b0 = *(const uint4*)(Bt + (size_t)(col0 + lr) * K + k0 + lc);
    uint4 b1 = *(const uint4*)(Bt + (size_t)(col0 + lr + 32) * K + k0 + lc);
    __syncthreads();
    *(uint4*)&As[lr][lc] = a0;
    *(uint4*)&As[lr + 32][lc] = a1;
    *(uint4*)&Bs[lr][lc] = b0;
    *(uint4*)&Bs[lr + 32][lc] = b1;
    __syncthreads();
#pragma unroll
    for (int kss = 0; kss < 2; ++kss) {
      bf16x8 bfr[2], afr[2];
#pragma unroll
      for (int nt = 0; nt < 2; ++nt)
        bfr[nt] = *(const bf16x8*)&Bs[nh + nt * 16 + ln][kss * 32 + quad * 8];
#pragma unroll
      for (int mt = 0; mt < 2; ++mt)
        afr[mt] = *(const bf16x8*)&As[mh + mt * 16 + ln][kss * 32 + quad * 8];
#pragma unroll
      for (int mt = 0; mt < 2; ++mt)
#pragma unroll
        for (int nt = 0; nt < 2; ++nt)
          acc[mt][nt] = __builtin_amdgcn_mfma_f32_16x16x32_bf16(
              afr[mt], bfr[nt], acc[mt][nt], 0, 0, 0);
    }
  }
  float dtv = dtp[0];
  float c2 = (1.f - ALPHA) * (1.f - 2.f * dtv);
  float c3b = (1.f - ALPHA) * 2.f * dtv / EPSILON;
#pragma unroll
  for (int mt = 0; mt < 2; ++mt)
#pragma unroll
    for (int nt = 0; nt < 2; ++nt) {
      int col = col0 + nh + nt * 16 + ln;
#pragma unroll
      for (int r = 0; r < 4; ++r) {
        int row = row0 + mh + mt * 16 + quad * 4 + r;
        float c3 = c3b / dv[row];
        Z[(size_t)row * N + col] =
            f2bf(c2 * x[(size_t)row * N + col] + c3 * acc[mt][nt][r]);
      }
    }
}

// pre = ALPHA*x + Z[M][K] @ fwTb[N][K]^T + cb*bias; writes fp32 out
__global__ __launch_bounds__(256) void k_gemmB(
    const unsigned short* __restrict__ A, const unsigned short* __restrict__ Bt,
    const float* __restrict__ x, const float* __restrict__ bias,
    const float* __restrict__ dtp, float* __restrict__ out,
    int M, int N, int K) {
  __shared__ unsigned short As[64][72];
  __shared__ unsigned short Bs[64][72];
  int tid = threadIdx.x;
  int w = tid >> 6, l = tid & 63;
  int ln = l & 15, quad = l >> 4;
  int mh = (w & 1) * 32, nh = (w >> 1) * 32;
  int row0 = blockIdx.y * 64, col0 = blockIdx.x * 64;
  int lr = tid >> 3, lc = (tid & 7) * 8;
  f32x4 acc[2][2] = {};
  for (int k0 = 0; k0 < K; k0 += 64) {
    uint4 a0 = *(const uint4*)(A + (size_t)(row0 + lr) * K + k0 + lc);
    uint4 a1 = *(const uint4*)(A + (size_t)(row0 + lr + 32) * K + k0 + lc);
    uint4 b0 = *(const uint4*)(Bt + (size_t)(col0 + lr) * K + k0 + lc);
    uint4 b1 = *(const uint4*)(Bt + (size_t)(col0 + lr + 32) * K + k0 + lc);
    __syncthreads();
    *(uint4*)&As[lr][lc] = a0;
    *(uint4*)&As[lr + 32][lc] = a1;
    *(uint4*)&Bs[lr][lc] = b0;
    *(uint4*)&Bs[lr + 32][lc] = b1;
    __syncthreads();
#pragma unroll
    for (int kss = 0; kss < 2; ++kss) {
      bf16x8 bfr[2], afr[2];
#pragma unroll
      for (int nt = 0; nt < 2; ++nt)
        bfr[nt] = *(const bf16x8*)&Bs[nh + nt * 16 + ln][kss * 32 + quad * 8];
#pragma unroll
      for (int mt = 0; mt < 2; ++mt)
        afr[mt] = *(const bf16x8*)&As[mh + mt * 16 + ln][kss * 32 + quad * 8];
#pragma unroll
      for (int mt = 0; mt < 2; ++mt)
#pragma unroll
        for (int nt = 0; nt < 2; ++nt)
          acc[mt][nt] = __builtin_amdgcn_mfma_f32_16x16x32_bf16(
              afr[mt], bfr[nt], acc[mt][nt], 0, 0, 0);
    }
  }
  float dtv = dtp[0];
  float cb = (1.f - ALPHA) * (1.f - 2.f * dtv) +
             (1.f - ALPHA) * 2.f * dtv / EPSILON;
#pragma unroll
  for (int mt = 0; mt < 2; ++mt)
#pragma unroll
    for (int nt = 0; nt < 2; ++nt) {
      int col = col0 + nh + nt * 16 + ln;
      float bv = cb * bias[col];
#pragma unroll
      for (int r = 0; r < 4; ++r) {
        int row = row0 + mh + mt * 16 + quad * 4 + r;
        size_t idx = (size_t)row * N + col;
        out[idx] = ALPHA * x[idx] + acc[mt][nt][r] + bv;
      }
    }
}

// In-place LayerNorm over rows of out (D elements, D/256 <= 4)
__global__ __launch_bounds__(256) void k_ln_rows(
    float* __restrict__ out, const float* __restrict__ g,
    const float* __restrict__ b, int D) {
  __shared__ float red[4];
  int i = blockIdx.x, tid = threadIdx.x;
  float vv[4];
  int nt = D / 256;
  float sum = 0.f;
  for (int t = 0; t < nt; ++t) {
    vv[t] = out[(size_t)i * D + tid + t * 256];
    sum += vv[t];
  }
  float mu = blk_reduce_sum(sum, red) / (float)D;
  float sq = 0.f;
  for (int t = 0; t < nt; ++t) { float d2 = vv[t] - mu; sq += d2 * d2; }
  float var = blk_reduce_sum(sq, red) / (float)D;
  float rs = rsqrtf(var + LN_EPS);
  for (int t = 0; t < nt; ++t) {
    int d0 = tid + t * 256;
    out[(size_t)i * D + d0] = (vv[t] - mu) * rs * g[d0] + b[d0];
  }
}

extern "C" void kernel_launch(void* const* d_in, const int* in_sizes, int n_in,
                              void* d_out, int out_size, void* d_ws, size_t ws_size,
                              hipStream_t stream) {
  const float* x = (const float*)d_in[0];
  const float* proj_w = (const float*)d_in[1];
  const float* proj_b = (const float*)d_in[2];
  const float* ln1_g = (const float*)d_in[3];
  const float* ln1_b = (const float*)d_in[4];
  const float* pi_w1 = (const float*)d_in[5];
  const float* pi_b1 = (const float*)d_in[6];
  const float* pi_w2 = (const float*)d_in[7];
  const float* pi_b2 = (const float*)d_in[8];
  const float* dt = (const float*)d_in[9];
  const float* f_w = (const float*)d_in[10];
  const float* f_b = (const float*)d_in[11];
  const float* ln2_g = (const float*)d_in[12];
  const float* ln2_b = (const float*)d_in[13];
  float* out = (float*)d_out;

  int D = in_sizes[11];      // 768
  int N = in_sizes[0] / D;   // 2048

  unsigned short* Kb = (unsigned short*)d_ws;                   // N*N bf16
  unsigned short* xvbT = Kb + (size_t)N * N;                    // D*N bf16
  unsigned short* fwTb = xvbT + (size_t)D * N;                  // D*D bf16
  unsigned short* Z = fwTb + (size_t)D * D;                     // N*D bf16
  float* xp = (float*)(Z + (size_t)N * D);                      // N*16
  float* s = xp + (size_t)N * 16;                               // N
  float* pi = s + N;                                            // N
  float* q = pi + N;                                            // N
  float* v = q + N;                                             // N
  float* dv = v + N;                                            // N

  int xvtB = (D / 32) * (N / 32);
  int tcvtB = (D / 32) * (D / 32);

  k_proj<<<N / 16, 256, 0, stream>>>(x, proj_w, proj_b, ln1_g, ln1_b, pi_w1,
                                     pi_b1, pi_w2, pi_b2, xp, s, pi, N, D);
  k_keps<<<N / 4, 256, 0, stream>>>(xp, s, pi, Kb, q, v, N);
  k_prep<<<N + xvtB + tcvtB, 256, 0, stream>>>(Kb, v, dv, x, xvbT, f_w, fwTb,
                                               N, D);
  k_gemmA<<<dim3(D / 64, N / 64), 256, 0, stream>>>(Kb, xvbT, x, dv, dt, Z,
                                                    N, D, N);
  k_gemmB<<<dim3(D / 64, N / 64), 256, 0, stream>>>(Z, fwTb, x, f_b, dt, out,
                                                    N, D, D);
  k_ln_rows<<<N, 256, 0, stream>>>(out, ln2_g, ln2_b, D);
}

// Round 6
// 159.392 us; speedup vs baseline: 2.1710x; 1.0128x over previous
//
#include <hip/hip_runtime.h>
#include <math.h>

#define EPSILON 0.3f
#define ALPHA 0.7f
#define LN_EPS 1e-5f

typedef __bf16 bf16x8 __attribute__((ext_vector_type(8)));
typedef float f32x4 __attribute__((ext_vector_type(4)));

__device__ __forceinline__ unsigned short f2bf(float f) {
  unsigned int u = __float_as_uint(f);
  return (unsigned short)((u + 0x7fffu + ((u >> 16) & 1u)) >> 16);
}
__device__ __forceinline__ unsigned int pack2(float lo, float hi) {
  return (unsigned int)f2bf(lo) | ((unsigned int)f2bf(hi) << 16);
}

// async 16B/lane global->LDS DMA; l must be wave-uniform (HW adds lane*16)
__device__ __forceinline__ void async16(const unsigned short* g,
                                        unsigned short* l) {
  __builtin_amdgcn_global_load_lds(
      (const __attribute__((address_space(1))) unsigned int*)g,
      (__attribute__((address_space(3))) unsigned int*)l, 16, 0, 0);
}

__device__ __forceinline__ float wave_reduce(float v) {
#pragma unroll
  for (int off = 32; off > 0; off >>= 1) v += __shfl_xor(v, off, 64);
  return v;
}

__device__ __forceinline__ float blk_reduce_sum(float v, float* red) {
  v = wave_reduce(v);
  int lane = threadIdx.x & 63, wid = threadIdx.x >> 6;
  __syncthreads();
  if (lane == 0) red[wid] = v;
  __syncthreads();
  float s = 0.f;
  int nw = (blockDim.x + 63) >> 6;
  for (int w = 0; w < nw; ++w) s += red[w];
  return s;
}

// blocks [0, N/16): 16 rows of proj -> LN -> ReLU -> xp, s ; pi head.
// blocks [N/16, ..): 32x32 transpose tiles fwTb[c][r] = bf16(f_w[r][c]).
__global__ __launch_bounds__(256) void k_proj(
    const float* __restrict__ x, const float* __restrict__ proj_w,
    const float* __restrict__ proj_b, const float* __restrict__ ln1_g,
    const float* __restrict__ ln1_b, const float* __restrict__ pi_w1,
    const float* __restrict__ pi_b1, const float* __restrict__ pi_w2,
    const float* __restrict__ pi_b2, const float* __restrict__ fw,
    unsigned short* __restrict__ fwTb, float* __restrict__ xp,
    float* __restrict__ s, float* __restrict__ pi, int N, int D) {
  __shared__ float xs[16][68];
  __shared__ float ws[64][20];
  __shared__ float ysh[16][17];
  __shared__ float xps[16][16];
  __shared__ float pr[16][4];
  int tid = threadIdx.x;
  int nProj = N / 16;
  if (blockIdx.x >= (unsigned)nProj) {
    // f_w transpose phase
    unsigned short(*tile)[33] = (unsigned short(*)[33])&ws[0][0];
    int t = blockIdx.x - nProj;
    int tx = tid & 31, ty = tid >> 5;
    int cols = D / 32;
    int c0 = (t % cols) * 32, r0 = (t / cols) * 32;
#pragma unroll
    for (int i = 0; i < 4; ++i) {
      int r = r0 + ty + i * 8;
      tile[ty + i * 8][tx] = f2bf(fw[(size_t)r * D + c0 + tx]);
    }
    __syncthreads();
#pragma unroll
    for (int i = 0; i < 4; ++i) {
      int cc = c0 + ty + i * 8;
      fwTb[(size_t)cc * D + r0 + tx] = tile[tx][ty + i * 8];
    }
    return;
  }
  int row0 = blockIdx.x * 16;
  int row = tid >> 4, l = tid & 15;
  int lane = tid & 63, w = tid >> 6;
  int skc = (tid & 15) * 4;
  int wk = tid >> 2, wl = (tid & 3) * 4;
  float acc = 0.f;
  for (int k0 = 0; k0 < D; k0 += 64) {
    float4 xv = *(const float4*)(x + (size_t)(row0 + row) * D + k0 + skc);
    float4 wv = *(const float4*)(proj_w + (size_t)(k0 + wk) * 16 + wl);
    __syncthreads();
    *(float4*)&xs[row][skc] = xv;
    *(float4*)&ws[wk][wl] = wv;
    __syncthreads();
#pragma unroll
    for (int kk = 0; kk < 64; kk += 4) {
      float4 a4 = *(const float4*)&xs[row][kk];
      acc += a4.x * ws[kk + 0][l];
      acc += a4.y * ws[kk + 1][l];
      acc += a4.z * ws[kk + 2][l];
      acc += a4.w * ws[kk + 3][l];
    }
  }
  float y = acc + proj_b[l];
  ysh[row][l] = y;
  __syncthreads();
  float mu = 0.f;
#pragma unroll
  for (int t = 0; t < 16; ++t) mu += ysh[row][t];
  mu *= (1.f / 16.f);
  float var = 0.f;
#pragma unroll
  for (int t = 0; t < 16; ++t) { float d2 = ysh[row][t] - mu; var += d2 * d2; }
  var *= (1.f / 16.f);
  float rstd = rsqrtf(var + LN_EPS);
  float xpv = fmaxf((y - mu) * rstd * ln1_g[l] + ln1_b[l], 0.f);
  xps[row][l] = xpv;
  xp[(size_t)(row0 + row) * 16 + l] = xpv;
  float sq = xpv * xpv;
  sq += __shfl_xor(sq, 8, 64);
  sq += __shfl_xor(sq, 4, 64);
  sq += __shfl_xor(sq, 2, 64);
  sq += __shfl_xor(sq, 1, 64);
  if ((lane & 15) == 0) s[row0 + row] = sq;
  __syncthreads();
  float w1r[3][16], b1r[3], w2r[3];
#pragma unroll
  for (int c = 0; c < 3; ++c) {
    int d0 = tid + c * 256;
    b1r[c] = pi_b1[d0];
    w2r[c] = pi_w2[d0];
#pragma unroll
    for (int t = 0; t < 16; ++t) w1r[c][t] = pi_w1[(size_t)t * D + d0];
  }
  float pacc[16];
#pragma unroll
  for (int r = 0; r < 16; ++r) pacc[r] = 0.f;
#pragma unroll
  for (int r = 0; r < 16; ++r) {
    float xv[16];
#pragma unroll
    for (int t4 = 0; t4 < 4; ++t4) {
      float4 xq = *(const float4*)&xps[r][t4 * 4];
      xv[t4 * 4 + 0] = xq.x; xv[t4 * 4 + 1] = xq.y;
      xv[t4 * 4 + 2] = xq.z; xv[t4 * 4 + 3] = xq.w;
    }
    float pa = 0.f;
#pragma unroll
    for (int c = 0; c < 3; ++c) {
      float h = b1r[c];
#pragma unroll
      for (int t = 0; t < 16; ++t) h += xv[t] * w1r[c][t];
      h = fmaxf(h, 0.f);
      pa += h * w2r[c];
    }
    pacc[r] = pa;
  }
#pragma unroll
  for (int r = 0; r < 16; ++r) {
    float pv = wave_reduce(pacc[r]);
    if (lane == 0) pr[r][w] = pv;
  }
  __syncthreads();
  if (tid < 16) {
    float tot = pr[tid][0] + pr[tid][1] + pr[tid][2] + pr[tid][3] + pi_b2[0];
    pi[row0 + tid] = 1.f / (1.f + expf(-tot));
  }
}

// 4 rows per block, 2 cols per thread; writes Kb bf16, v[i] = pi[i]/rowsum.
__global__ __launch_bounds__(256) void k_keps(
    const float* __restrict__ xp, const float* __restrict__ s,
    const float* __restrict__ pi, unsigned short* __restrict__ Kb,
    float* __restrict__ v, int N) {
  __shared__ float qs[4][4];
  int i0 = blockIdx.x * 4;
  int tid = threadIdx.x, lane = tid & 63, w = tid >> 6;
  float a[4][16], si[4];
#pragma unroll
  for (int r = 0; r < 4; ++r) {
    const float* ap = xp + (size_t)(i0 + r) * 16;
#pragma unroll
    for (int t = 0; t < 16; ++t) a[r][t] = ap[t];
    si[r] = s[i0 + r];
  }
  const float c = 1.f / (4.f * EPSILON);
  float qa[4] = {0.f, 0.f, 0.f, 0.f};
  for (int it = 0; it < N / 512; ++it) {
    int j = it * 512 + tid * 2;
    const float4* bp = (const float4*)(xp + (size_t)j * 16);
    float4 b0 = bp[0], b1 = bp[1], b2 = bp[2], b3 = bp[3];
    float4 c0 = bp[4], c1 = bp[5], c2 = bp[6], c3 = bp[7];
    float bv[16] = {b0.x, b0.y, b0.z, b0.w, b1.x, b1.y, b1.z, b1.w,
                    b2.x, b2.y, b2.z, b2.w, b3.x, b3.y, b3.z, b3.w};
    float cv[16] = {c0.x, c0.y, c0.z, c0.w, c1.x, c1.y, c1.z, c1.w,
                    c2.x, c2.y, c2.z, c2.w, c3.x, c3.y, c3.z, c3.w};
    float sj0 = s[j], sj1 = s[j + 1];
#pragma unroll
    for (int r = 0; r < 4; ++r) {
      float d0 = 0.f, d1 = 0.f;
#pragma unroll
      for (int t = 0; t < 16; ++t) { d0 += a[r][t] * bv[t]; d1 += a[r][t] * cv[t]; }
      float k0 = expf(-c * (si[r] + sj0 - 2.f * d0));
      float k1 = expf(-c * (si[r] + sj1 - 2.f * d1));
      *(unsigned int*)(Kb + (size_t)(i0 + r) * N + j) = pack2(k0, k1);
      qa[r] += k0 + k1;
    }
  }
#pragma unroll
  for (int r = 0; r < 4; ++r) {
    float t = wave_reduce(qa[r]);
    if (lane == 0) qs[r][w] = t;
  }
  __syncthreads();
  if (tid < 4) {
    float tot = qs[tid][0] + qs[tid][1] + qs[tid][2] + qs[tid][3];
    v[i0 + tid] = pi[i0 + tid] / tot;
  }
}

// blocks [0, N): dv[i] = sum_j bf16(Kb[i][j])*v[j] + 1e-5
// blocks [N, ..): xvbT[d][j] = bf16(v[j] * x[j][d]) (32x32 transpose tiles)
__global__ __launch_bounds__(256) void k_prep(
    const unsigned short* __restrict__ Kb, const float* __restrict__ v,
    float* __restrict__ dv, const float* __restrict__ x,
    unsigned short* __restrict__ xvbT, int N, int D) {
  __shared__ float sh[544];
  int bid = blockIdx.x, tid = threadIdx.x;
  if (bid < N) {
    int i = bid;
    float acc = 0.f;
    for (int j8 = tid * 8; j8 < N; j8 += 256 * 8) {
      uint4 kv4 = *(const uint4*)(Kb + (size_t)i * N + j8);
      float4 va = *(const float4*)(v + j8);
      float4 vb = *(const float4*)(v + j8 + 4);
      unsigned int u;
      u = kv4.x;
      acc += __uint_as_float(u << 16) * va.x + __uint_as_float(u & 0xffff0000u) * va.y;
      u = kv4.y;
      acc += __uint_as_float(u << 16) * va.z + __uint_as_float(u & 0xffff0000u) * va.w;
      u = kv4.z;
      acc += __uint_as_float(u << 16) * vb.x + __uint_as_float(u & 0xffff0000u) * vb.y;
      u = kv4.w;
      acc += __uint_as_float(u << 16) * vb.z + __uint_as_float(u & 0xffff0000u) * vb.w;
    }
    float tot = blk_reduce_sum(acc, sh);
    if (tid == 0) dv[i] = tot + 1e-5f;
  } else {
    int t = bid - N;
    unsigned short(*tile)[33] = (unsigned short(*)[33])sh;
    int tx = tid & 31, ty = tid >> 5;
    int cols = D / 32;
    int c0 = (t % cols) * 32;  // over D
    int r0 = (t / cols) * 32;  // over N
#pragma unroll
    for (int i = 0; i < 4; ++i) {
      int r = r0 + ty + i * 8;
      tile[ty + i * 8][tx] = f2bf(v[r] * x[(size_t)r * D + c0 + tx]);
    }
    __syncthreads();
#pragma unroll
    for (int i = 0; i < 4; ++i) {
      int cc = c0 + ty + i * 8;
      xvbT[(size_t)cc * N + r0 + tx] = tile[tx][ty + i * 8];
    }
  }
}

// Shared async-staged 64x64 K-loop (BK=64, XOR-swizzled LDS, global_load_lds).
// Wave w stages rows [w*8,w*8+8) and [32+w*8,+8) of both tiles; lane l writes
// LDS chunk (l&7) of row (l>>3) from global chunk ((l&7)^(l>>3)).
#define GEMM_KLOOP(Aptr, Bptr, Kdim)                                          \
  int tid = threadIdx.x;                                                      \
  int w = tid >> 6, l = tid & 63;                                             \
  int ln = l & 15, quad = l >> 4;                                             \
  int mh = (w & 1) * 32, nh = (w >> 1) * 32;                                  \
  int row0 = blockIdx.y * 64, col0 = blockIdx.x * 64;                         \
  int sr = l >> 3, sj = l & 7;                                                \
  int swz = (sj ^ sr) * 8;                                                    \
  const unsigned short* gA0 = Aptr + (size_t)(row0 + w * 8 + sr) * Kdim + swz;\
  const unsigned short* gB0 = Bptr + (size_t)(col0 + w * 8 + sr) * Kdim + swz;\
  const unsigned short* gA1 = gA0 + (size_t)32 * Kdim;                        \
  const unsigned short* gB1 = gB0 + (size_t)32 * Kdim;                        \
  unsigned short* lA0 = As + w * 8 * 64;                                      \
  unsigned short* lA1 = As + (32 + w * 8) * 64;                               \
  unsigned short* lB0 = Bs + w * 8 * 64;                                      \
  unsigned short* lB1 = Bs + (32 + w * 8) * 64;                               \
  f32x4 acc[2][2] = {};                                                       \
  for (int k0 = 0; k0 < Kdim; k0 += 64) {                                     \
    __syncthreads();                                                          \
    async16(gA0 + k0, lA0);                                                   \
    async16(gA1 + k0, lA1);                                                   \
    async16(gB0 + k0, lB0);                                                   \
    async16(gB1 + k0, lB1);                                                   \
    __syncthreads();                                                          \
    _Pragma("unroll")                                                         \
    for (int ks = 0; ks < 2; ++ks) {                                          \
      bf16x8 bfr[2], afr[2];                                                  \
      _Pragma("unroll")                                                       \
      for (int nt = 0; nt < 2; ++nt) {                                        \
        int r = nh + nt * 16 + ln;                                            \
        int cix = (ks * 4 + quad) ^ (r & 7);                                  \
        bfr[nt] = *(const bf16x8*)&Bs[r * 64 + cix * 8];                      \
      }                                                                       \
      _Pragma("unroll")                                                       \
      for (int mt = 0; mt < 2; ++mt) {                                        \
        int r = mh + mt * 16 + ln;                                            \
        int cix = (ks * 4 + quad) ^ (r & 7);                                  \
        afr[mt] = *(const bf16x8*)&As[r * 64 + cix * 8];                      \
      }                                                                       \
      _Pragma("unroll")                                                       \
      for (int mt = 0; mt < 2; ++mt)                                          \
        _Pragma("unroll")                                                     \
        for (int nt = 0; nt < 2; ++nt)                                        \
          acc[mt][nt] = __builtin_amdgcn_mfma_f32_16x16x32_bf16(              \
              afr[mt], bfr[nt], acc[mt][nt], 0, 0, 0);                        \
    }                                                                         \
  }

// Y = Kb @ xvbT^T; Z[row][col] = bf16(c2*x[row][col] + (c3/dv[row])*acc)
__global__ __launch_bounds__(256) void k_gemmA(
    const unsigned short* __restrict__ A, const unsigned short* __restrict__ Bt,
    const float* __restrict__ x, const float* __restrict__ dv,
    const float* __restrict__ dtp, unsigned short* __restrict__ Z,
    int M, int N, int K) {
  __shared__ unsigned short As[64 * 64];
  __shared__ unsigned short Bs[64 * 64];
  GEMM_KLOOP(A, Bt, K)
  float dtv = dtp[0];
  float c2 = (1.f - ALPHA) * (1.f - 2.f * dtv);
  float c3b = (1.f - ALPHA) * 2.f * dtv / EPSILON;
#pragma unroll
  for (int mt = 0; mt < 2; ++mt)
#pragma unroll
    for (int nt = 0; nt < 2; ++nt) {
      int col = col0 + nh + nt * 16 + ln;
#pragma unroll
      for (int r = 0; r < 4; ++r) {
        int row = row0 + mh + mt * 16 + quad * 4 + r;
        float c3 = c3b / dv[row];
        Z[(size_t)row * N + col] =
            f2bf(c2 * x[(size_t)row * N + col] + c3 * acc[mt][nt][r]);
      }
    }
}

// pre = ALPHA*x + Z @ fwTb^T + cb*bias; writes fp32 out
__global__ __launch_bounds__(256) void k_gemmB(
    const unsigned short* __restrict__ A, const unsigned short* __restrict__ Bt,
    const float* __restrict__ x, const float* __restrict__ bias,
    const float* __restrict__ dtp, float* __restrict__ out,
    int M, int N, int K) {
  __shared__ unsigned short As[64 * 64];
  __shared__ unsigned short Bs[64 * 64];
  GEMM_KLOOP(A, Bt, K)
  float dtv = dtp[0];
  float cb = (1.f - ALPHA) * (1.f - 2.f * dtv) +
             (1.f - ALPHA) * 2.f * dtv / EPSILON;
#pragma unroll
  for (int mt = 0; mt < 2; ++mt)
#pragma unroll
    for (int nt = 0; nt < 2; ++nt) {
      int col = col0 + nh + nt * 16 + ln;
      float bv = cb * bias[col];
#pragma unroll
      for (int r = 0; r < 4; ++r) {
        int row = row0 + mh + mt * 16 + quad * 4 + r;
        size_t idx = (size_t)row * N + col;
        out[idx] = ALPHA * x[idx] + acc[mt][nt][r] + bv;
      }
    }
}

// In-place LayerNorm over rows of out (D elements, D/256 <= 4)
__global__ __launch_bounds__(256) void k_ln_rows(
    float* __restrict__ out, const float* __restrict__ g,
    const float* __restrict__ b, int D) {
  __shared__ float red[4];
  int i = blockIdx.x, tid = threadIdx.x;
  float vv[4];
  int nt = D / 256;
  float sum = 0.f;
  for (int t = 0; t < nt; ++t) {
    vv[t] = out[(size_t)i * D + tid + t * 256];
    sum += vv[t];
  }
  float mu = blk_reduce_sum(sum, red) / (float)D;
  float sq = 0.f;
  for (int t = 0; t < nt; ++t) { float d2 = vv[t] - mu; sq += d2 * d2; }
  float var = blk_reduce_sum(sq, red) / (float)D;
  float rs = rsqrtf(var + LN_EPS);
  for (int t = 0; t < nt; ++t) {
    int d0 = tid + t * 256;
    out[(size_t)i * D + d0] = (vv[t] - mu) * rs * g[d0] + b[d0];
  }
}

extern "C" void kernel_launch(void* const* d_in, const int* in_sizes, int n_in,
                              void* d_out, int out_size, void* d_ws, size_t ws_size,
                              hipStream_t stream) {
  const float* x = (const float*)d_in[0];
  const float* proj_w = (const float*)d_in[1];
  const float* proj_b = (const float*)d_in[2];
  const float* ln1_g = (const float*)d_in[3];
  const float* ln1_b = (const float*)d_in[4];
  const float* pi_w1 = (const float*)d_in[5];
  const float* pi_b1 = (const float*)d_in[6];
  const float* pi_w2 = (const float*)d_in[7];
  const float* pi_b2 = (const float*)d_in[8];
  const float* dt = (const float*)d_in[9];
  const float* f_w = (const float*)d_in[10];
  const float* f_b = (const float*)d_in[11];
  const float* ln2_g = (const float*)d_in[12];
  const float* ln2_b = (const float*)d_in[13];
  float* out = (float*)d_out;

  int D = in_sizes[11];      // 768
  int N = in_sizes[0] / D;   // 2048

  unsigned short* Kb = (unsigned short*)d_ws;                   // N*N bf16
  unsigned short* xvbT = Kb + (size_t)N * N;                    // D*N bf16
  unsigned short* fwTb = xvbT + (size_t)D * N;                  // D*D bf16
  unsigned short* Z = fwTb + (size_t)D * D;                     // N*D bf16
  float* xp = (float*)(Z + (size_t)N * D);                      // N*16
  float* s = xp + (size_t)N * 16;                               // N
  float* pi = s + N;                                            // N
  float* v = pi + N;                                            // N
  float* dv = v + N;                                            // N

  int fwB = (D / 32) * (D / 32);
  int xvtB = (D / 32) * (N / 32);

  k_proj<<<N / 16 + fwB, 256, 0, stream>>>(x, proj_w, proj_b, ln1_g, ln1_b,
                                           pi_w1, pi_b1, pi_w2, pi_b2, f_w,
                                           fwTb, xp, s, pi, N, D);
  k_keps<<<N / 4, 256, 0, stream>>>(xp, s, pi, Kb, v, N);
  k_prep<<<N + xvtB, 256, 0, stream>>>(Kb, v, dv, x, xvbT, N, D);
  k_gemmA<<<dim3(D / 64, N / 64), 256, 0, stream>>>(Kb, xvbT, x, dv, dt, Z,
                                                    N, D, N);
  k_gemmB<<<dim3(D / 64, N / 64), 256, 0, stream>>>(Z, fwTb, x, f_b, dt, out,
                                                    N, D, D);
  k_ln_rows<<<N, 256, 0, stream>>>(out, ln2_g, ln2_b, D);
}